// Round 9
// baseline (327.749 us; speedup 1.0000x reference)
//
#include <hip/hip_runtime.h>
#include <stdint.h>
#include <math.h>

// Problem constants
#define N_SEQ 4096
#define EDIM  2048
#define NH    16
#define HD    128

typedef __attribute__((ext_vector_type(8))) short bf16x8;
typedef __attribute__((ext_vector_type(4))) float f32x4;

#define AS1 __attribute__((address_space(1)))
#define AS3 __attribute__((address_space(3)))

__device__ __forceinline__ void gll16(const unsigned short* g, unsigned short* l) {
    __builtin_amdgcn_global_load_lds((const AS1 unsigned int*)g,
                                     (AS3 unsigned int*)l, 16, 0, 0);
}

__device__ __forceinline__ unsigned short f2bf(float f) {
    union { float f; unsigned u; } v; v.f = f;
    unsigned r = v.u + 0x7FFFu + ((v.u >> 16) & 1u);
    return (unsigned short)(r >> 16);
}
__device__ __forceinline__ float bf2f(unsigned short h) {
    union { unsigned u; float f; } v; v.u = ((unsigned)h) << 16;
    return v.f;
}

// ---------------------------------------------------------------- convert x
__global__ void k_convert_x(const float* __restrict__ x,
                            unsigned short* __restrict__ xb, int n4) {
    int i = blockIdx.x * blockDim.x + threadIdx.x;
    int stride = gridDim.x * blockDim.x;
    for (; i < n4; i += stride) {
        float4 v = ((const float4*)x)[i];
        ushort4 o;
        o.x = f2bf(v.x); o.y = f2bf(v.y); o.z = f2bf(v.z); o.w = f2bf(v.w);
        ((ushort4*)xb)[i] = o;
    }
}

// ---------------------------------------------- transpose f32 (RxC) -> bf16 (CxR)
__global__ void k_transpose_f32_bf16(const float* __restrict__ in,
                                     unsigned short* __restrict__ out,
                                     int R, int C) {
    __shared__ unsigned short Ls[64][68];
    const int c0 = blockIdx.x * 64, r0 = blockIdx.y * 64;
    const int t = threadIdx.x;
    #pragma unroll
    for (int i = 0; i < 4; ++i) {
        int ch = i * 256 + t;              // 1024 float4 chunks
        int r = ch >> 4, c4 = (ch & 15) * 4;
        float4 v = *(const float4*)&in[(size_t)(r0 + r) * C + c0 + c4];
        ushort4 o;
        o.x = f2bf(v.x); o.y = f2bf(v.y); o.z = f2bf(v.z); o.w = f2bf(v.w);
        *(ushort4*)&Ls[r][c4] = o;
    }
    __syncthreads();
    #pragma unroll
    for (int i = 0; i < 2; ++i) {
        int ch = i * 256 + t;              // 512 chunks of 8 bf16
        int rr = ch >> 3, c8 = (ch & 7) * 8;
        unsigned short vals[8];
        #pragma unroll
        for (int j = 0; j < 8; ++j) vals[j] = Ls[c8 + j][rr];
        uint4 pk;
        pk.x = (unsigned)vals[0] | ((unsigned)vals[1] << 16);
        pk.y = (unsigned)vals[2] | ((unsigned)vals[3] << 16);
        pk.z = (unsigned)vals[4] | ((unsigned)vals[5] << 16);
        pk.w = (unsigned)vals[6] | ((unsigned)vals[7] << 16);
        *(uint4*)&out[(size_t)(c0 + rr) * R + r0 + c8] = pk;
    }
}

// ---------------------------------------------------------------- bt GEMM
// C[M,N] = A[M,K] * Bt[N,K]^T  (bf16 in, f32 acc, bf16 or f32 out)
template<int F32OUT>
__launch_bounds__(256, 2)
__global__ void k_gemm_bt(const unsigned short* __restrict__ A,
                          const unsigned short* __restrict__ Bt,
                          void* __restrict__ C,
                          int M, int N, int K) {
    __shared__ unsigned short sh[2 * 128 * 64];   // As | Bs, linear [128][64]
    unsigned short* As = sh;
    unsigned short* Bs = sh + 128 * 64;

    const int t = threadIdx.x;
    const int wave = t >> 6, lane = t & 63;
    const int wm = wave >> 1, wn = wave & 1;
    const int lg = lane >> 4, lr = lane & 15;

    // XCD-aware bijective swizzle (nwg % 8 == 0 for all our grids)
    const int nbx = gridDim.x;
    const int nwg = nbx * gridDim.y;
    int bid = blockIdx.y * nbx + blockIdx.x;
    int swz = (bid & 7) * (nwg >> 3) + (bid >> 3);
    const int m0 = (swz / nbx) * 128;
    const int n0 = (swz % nbx) * 128;

    const unsigned short* aptr = A  + (size_t)m0 * K;
    const unsigned short* bptr = Bt + (size_t)n0 * K;

    f32x4 acc[4][4];
    #pragma unroll
    for (int i = 0; i < 4; ++i)
        #pragma unroll
        for (int j = 0; j < 4; ++j) acc[i][j] = f32x4{0.f, 0.f, 0.f, 0.f};

    // per-thread staging geometry (loop-invariant)
    int schr[4], srow[4], scb[4];
    #pragma unroll
    for (int i = 0; i < 4; ++i) {
        int ch = (i * 4 + wave) * 64 + lane;   // 0..1023, wave-uniform base + lane
        schr[i] = ch;
        srow[i] = ch >> 3;
        scb[i]  = (ch & 7) ^ ((ch >> 3) & 7);  // inverse-swizzled source col-block
    }

    const int nkb = K >> 6;
    for (int kb = 0; kb < nkb; ++kb) {
        __syncthreads();   // previous iter's ds_reads done before overwrite
        #pragma unroll
        for (int i = 0; i < 4; ++i) {
            const size_t goff = (size_t)srow[i] * K + (size_t)kb * 64 + scb[i] * 8;
            gll16(&aptr[goff], &As[schr[i] * 8]);
            gll16(&bptr[goff], &Bs[schr[i] * 8]);
        }
        __syncthreads();   // drains vmcnt+lgkm (compiler-inserted before barrier)

        #pragma unroll
        for (int kk = 0; kk < 2; ++kk) {
            bf16x8 af[4], bf[4];
            const int cbx = ((kk * 4 + lg) ^ (lr & 7)) * 8;  // swizzled read col
            #pragma unroll
            for (int i = 0; i < 4; ++i) {
                af[i] = *(const bf16x8*)&As[(wm * 64 + i * 16 + lr) * 64 + cbx];
                bf[i] = *(const bf16x8*)&Bs[(wn * 64 + i * 16 + lr) * 64 + cbx];
            }
            #pragma unroll
            for (int i = 0; i < 4; ++i)
                #pragma unroll
                for (int j = 0; j < 4; ++j)
                    acc[i][j] = __builtin_amdgcn_mfma_f32_16x16x32_bf16(af[i], bf[j], acc[i][j], 0, 0, 0);
        }
    }

    if (F32OUT) {
        #pragma unroll
        for (int i = 0; i < 4; ++i) {
            int row0 = m0 + wm * 64 + i * 16 + lg * 4;
            #pragma unroll
            for (int j = 0; j < 4; ++j) {
                int col = n0 + wn * 64 + j * 16 + lr;
                #pragma unroll
                for (int r = 0; r < 4; ++r)
                    ((float*)C)[(size_t)(row0 + r) * N + col] = acc[i][j][r];
            }
        }
    } else {
        // stage bf16 C-tile in LDS, write out coalesced uint4 rows
        __syncthreads();
        unsigned short* Cs = sh;     // [128][128]
        #pragma unroll
        for (int i = 0; i < 4; ++i) {
            #pragma unroll
            for (int j = 0; j < 4; ++j) {
                int col = wn * 64 + j * 16 + lr;
                #pragma unroll
                for (int r = 0; r < 4; ++r)
                    Cs[(wm * 64 + i * 16 + lg * 4 + r) * 128 + col] = f2bf(acc[i][j][r]);
            }
        }
        __syncthreads();
        #pragma unroll
        for (int i = 0; i < 8; ++i) {
            int ch = i * 256 + t;             // 2048 chunks of 8 shorts
            int row = ch >> 4, c8 = (ch & 15) * 8;
            *(uint4*)&((unsigned short*)C)[(size_t)(m0 + row) * N + n0 + c8] =
                *(const uint4*)&Cs[row * 128 + c8];
        }
    }
}

// ------------------------------------------------------- RoPE + LayerNorm (q,k)
__global__ void k_ropeln(const unsigned short* __restrict__ proj,
                         const float* __restrict__ ln_scale,
                         const float* __restrict__ ln_bias,
                         unsigned short* __restrict__ Qh,
                         unsigned short* __restrict__ Kh) {
    const int n = blockIdx.x;
    const int wave = threadIdx.x >> 6, lane = threadIdx.x & 63;
    float inv = expf(-((float)(2 * lane) / 128.0f) * 9.210340371976184f);
    float ang = (float)n * inv;
    float c = cosf(ang), s = sinf(ang);
    const float sc1 = ln_scale[lane], sc2 = ln_scale[lane + 64];
    const float b1 = ln_bias[lane],  b2 = ln_bias[lane + 64];

    for (int r = wave; r < 32; r += 4) {
        int h = r >> 1, qk = r & 1;
        const unsigned short* src = proj + (size_t)n * (3 * EDIM) + qk * EDIM + h * HD;
        float x1 = bf2f(src[lane]), x2 = bf2f(src[lane + 64]);
        float o1 = x1 * c - x2 * s;
        float o2 = x1 * s + x2 * c;
        float sum = o1 + o2, sq = o1 * o1 + o2 * o2;
        #pragma unroll
        for (int d = 1; d < 64; d <<= 1) {
            sum += __shfl_xor(sum, d);
            sq  += __shfl_xor(sq, d);
        }
        float mean = sum * (1.0f / 128.0f);
        float var = sq * (1.0f / 128.0f) - mean * mean;
        float rstd = rsqrtf(var + 1e-5f);
        float y1 = (o1 - mean) * rstd * sc1 + b1;
        float y2 = (o2 - mean) * rstd * sc2 + b2;
        unsigned short* dst = (qk ? Kh : Qh) + ((size_t)h * N_SEQ + n) * HD;
        dst[lane]      = f2bf(y1);
        dst[lane + 64] = f2bf(y2);
    }
}

// ---------------------------------------------------- V transpose: [n][d] -> [d][n]
// Writes Vt with the PV k-permutation baked into each 64-key tile:
// tile position p*8+i  <-  k = 32*(p>>2) + 16*(i>>2) + 4*(p&3) + (i&3)
// so attn's V B-fragment (s2,lg) is ONE contiguous b128 chunk c = s2*4+lg.
__global__ void k_vtrans(const unsigned short* __restrict__ proj,
                         unsigned short* __restrict__ Vt) {
    __shared__ unsigned short Ls[64][136];
    const int h = blockIdx.y;
    const int n0 = blockIdx.x * 64;
    const int t = threadIdx.x;
    #pragma unroll
    for (int i = 0; i < 4; ++i) {
        int ch = i * 256 + t;
        int r = ch >> 4, d0 = (ch & 15) * 8;
        uint4 v = *(const uint4*)&proj[(size_t)(n0 + r) * (3 * EDIM) + 2 * EDIM + h * HD + d0];
        *(uint4*)&Ls[r][d0] = v;
    }
    __syncthreads();
    #pragma unroll
    for (int i = 0; i < 4; ++i) {
        int ch = i * 256 + t;
        int d = ch >> 3, p = ch & 7;
        unsigned short vals[8];
        #pragma unroll
        for (int j = 0; j < 8; ++j) {
            int ko = 32 * (p >> 2) + 16 * (j >> 2) + 4 * (p & 3) + (j & 3);
            vals[j] = Ls[ko][d];
        }
        uint4 pk;
        pk.x = (unsigned)vals[0] | ((unsigned)vals[1] << 16);
        pk.y = (unsigned)vals[2] | ((unsigned)vals[3] << 16);
        pk.z = (unsigned)vals[4] | ((unsigned)vals[5] << 16);
        pk.w = (unsigned)vals[6] | ((unsigned)vals[7] << 16);
        *(uint4*)&Vt[((size_t)h * HD + d) * N_SEQ + n0 + p * 8] = pk;
    }
}

// ------------------------------------------------------- polynomial attention
// Qh,Kh: [NH][N_SEQ][HD], Vt: [NH][HD][N_SEQ] (k-permuted tiles). O: [N_SEQ][EDIM].
// v8: 256-row q-tile, 8 waves (512 thr), ONE block per CU (grid 256) -> the
// heavy causal chain always has 2 waves/SIMD. Ring-4 K/V LDS buffers (128KB),
// prefetch distance 2, counted vmcnt(8) that never drains in steady state,
// ONE barrier per iteration. Per-wave compute identical to v7 (in-register P).
__launch_bounds__(512, 4)
__global__ void k_attn(const unsigned short* __restrict__ Qh,
                       const unsigned short* __restrict__ Kh,
                       const unsigned short* __restrict__ Vt,
                       unsigned short* __restrict__ O) {
    // pool: K[4][64][128] | V[4][128][64]  = 128 KB (epilogue reuses as Cs)
    __shared__ unsigned short pool[8 * 8192];

    const int t = threadIdx.x;
    const int w = t >> 6, lane = t & 63;
    const int lg = lane >> 4, lr = lane & 15;

    // block decode: 256 blocks = 1/CU. b&7 = XCD = h>>1 (2 heads per XCD).
    const int b = blockIdx.x;
    const int h = (b & 7) * 2 + ((b >> 3) & 1);
    const int qq = b >> 4;          // 0..15
    const int qb = 15 - qq;         // heavy tiles first in dispatch order
    const int q0 = qb * 256;
    const int qbase = q0 + w * 32;  // this wave's first q-row

    // Q fragments in registers (wave's 32 queries x 128 d)
    bf16x8 qf[2][4];
    #pragma unroll
    for (int mi = 0; mi < 2; ++mi)
        #pragma unroll
        for (int kk = 0; kk < 4; ++kk)
            qf[mi][kk] = *(const bf16x8*)&Qh[((size_t)h * N_SEQ + qbase + mi * 16 + lr) * HD + kk * 32 + lg * 8];

    f32x4 acc[2][8];
    #pragma unroll
    for (int i = 0; i < 2; ++i)
        #pragma unroll
        for (int j = 0; j < 8; ++j) acc[i][j] = f32x4{0.f, 0.f, 0.f, 0.f};
    f32x4 accd[2];
    accd[0] = f32x4{0.f, 0.f, 0.f, 0.f};
    accd[1] = f32x4{0.f, 0.f, 0.f, 0.f};

    // ones B-fragment: row-sum lands in output col 0 (k-permutation-invariant)
    bf16x8 onesf;
    {
        short ov = (lr == 0) ? (short)0x3F80 : (short)0;
        #pragma unroll
        for (int j = 0; j < 8; ++j) onesf[j] = ov;
    }

    // staging geometry: per tile K = 1024 chunks (2/thread @512thr), V = 1024
    // chunks (2/thread). LDS linear dest (wave-uniform base + lane*16B);
    // swizzle pre-applied to the global source chunk (involution).
    int kch[2], vch[2];
    const unsigned short* kg[2];
    const unsigned short* vg[2];
    #pragma unroll
    for (int i = 0; i < 2; ++i) {
        int ch = i * 512 + t;
        kch[i] = ch;
        int r = ch >> 4, p = ch & 15;
        int csrc = (p & 8) | ((p ^ r) & 7);
        kg[i] = Kh + ((size_t)h * N_SEQ + r) * HD + csrc * 8;
    }
    #pragma unroll
    for (int i = 0; i < 2; ++i) {
        int ch = i * 512 + t;
        vch[i] = ch;
        int d = ch >> 3, p2 = ch & 7;
        int c2src = (p2 ^ d) & 7;
        vg[i] = Vt + ((size_t)h * HD + d) * N_SEQ + c2src * 8;
    }

    const int nkb = 4 * qb + 4;   // multiple of 4

    union U8 { unsigned u[4]; bf16x8 v; };

    // stage tile T into ring slot s (4 loads/thread)
    auto stage = [&](int T, int slot) {
        unsigned short* Kn = pool + slot * 8192;
        unsigned short* Vn = pool + 32768 + slot * 8192;
        const size_t koff = (size_t)T * 64 * HD;
        const size_t voff = (size_t)T * 64;
        #pragma unroll
        for (int i = 0; i < 2; ++i) gll16(kg[i] + koff, Kn + kch[i] * 8);
        #pragma unroll
        for (int i = 0; i < 2; ++i) gll16(vg[i] + voff, Vn + vch[i] * 8);
    };

    auto compute = [&](int k0, int slot) {
        const unsigned short* Kc = pool + slot * 8192;
        const unsigned short* Vc = pool + 32768 + slot * 8192;
        // ---- S^T = K Q^T (swapped): lane holds S[k = 16nj+4lg+r][q = 16mi+lr]
        f32x4 sa[2][4];
        #pragma unroll
        for (int i = 0; i < 2; ++i)
            #pragma unroll
            for (int j = 0; j < 4; ++j) sa[i][j] = f32x4{0.f, 0.f, 0.f, 0.f};
        #pragma unroll
        for (int nn = 0; nn < 2; ++nn) {
            bf16x8 kf[2][4];
            #pragma unroll
            for (int nj = 0; nj < 2; ++nj)
                #pragma unroll
                for (int kk = 0; kk < 4; ++kk) {
                    int row = (nn * 2 + nj) * 16 + lr;
                    int c = kk * 4 + lg;
                    int cs = (c & 8) | ((c ^ row) & 7);
                    kf[nj][kk] = *(const bf16x8*)&Kc[row * 128 + cs * 8];
                }
            __builtin_amdgcn_s_setprio(1);
            #pragma unroll
            for (int kk = 0; kk < 4; ++kk)
                #pragma unroll
                for (int nj = 0; nj < 2; ++nj)
                    #pragma unroll
                    for (int mi = 0; mi < 2; ++mi)
                        sa[mi][nn * 2 + nj] = __builtin_amdgcn_mfma_f32_16x16x32_bf16(
                            kf[nj][kk], qf[mi][kk], sa[mi][nn * 2 + nj], 0, 0, 0);
            __builtin_amdgcn_s_setprio(0);
        }

        // ---- mask + ^4 + pack to bf16 pairs, all in registers.
        unsigned wreg[2][4][2];
        const bool nomask = (k0 + 63 <= qbase);
        #pragma unroll
        for (int mi = 0; mi < 2; ++mi)
            #pragma unroll
            for (int nj = 0; nj < 4; ++nj) {
                float p[4];
                #pragma unroll
                for (int r = 0; r < 4; ++r) {
                    float sv = sa[mi][nj][r];
                    float t2 = sv * sv;
                    p[r] = t2 * t2;
                    if (!nomask) {
                        int gk = k0 + nj * 16 + lg * 4 + r;
                        int gq = qbase + mi * 16 + lr;
                        p[r] = (gk <= gq) ? p[r] : 0.0f;
                    }
                }
                asm("v_cvt_pk_bf16_f32 %0, %1, %2" : "=v"(wreg[mi][nj][0]) : "v"(p[0]), "v"(p[1]));
                asm("v_cvt_pk_bf16_f32 %0, %1, %2" : "=v"(wreg[mi][nj][1]) : "v"(p[2]), "v"(p[3]));
            }

        // ---- O += P V, denom += P * ones.  Vt's baked tile permutation makes
        // each B-frag one b128 at chunk c = s2*4+lg (XOR-swizzled).
        #pragma unroll
        for (int s2 = 0; s2 < 2; ++s2) {
            bf16x8 pa[2];
            #pragma unroll
            for (int mi = 0; mi < 2; ++mi) {
                U8 u;
                u.u[0] = wreg[mi][2 * s2][0];
                u.u[1] = wreg[mi][2 * s2][1];
                u.u[2] = wreg[mi][2 * s2 + 1][0];
                u.u[3] = wreg[mi][2 * s2 + 1][1];
                pa[mi] = u.v;
            }
            __builtin_amdgcn_s_setprio(1);
            #pragma unroll
            for (int ni = 0; ni < 8; ++ni) {
                int d = ni * 16 + lr;
                int cs = ((s2 * 4 + lg) ^ (d & 7)) & 7;
                bf16x8 vf = *(const bf16x8*)&Vc[d * 64 + cs * 8];
                #pragma unroll
                for (int mi = 0; mi < 2; ++mi)
                    acc[mi][ni] = __builtin_amdgcn_mfma_f32_16x16x32_bf16(pa[mi], vf, acc[mi][ni], 0, 0, 0);
            }
            #pragma unroll
            for (int mi = 0; mi < 2; ++mi)
                accd[mi] = __builtin_amdgcn_mfma_f32_16x16x32_bf16(pa[mi], onesf, accd[mi], 0, 0, 0);
            __builtin_amdgcn_s_setprio(0);
        }
    };

    // prologue: stage tiles 0 and 1 (8 loads in flight)
    stage(0, 0);
    stage(1, 1);

    // ring-4, prefetch distance 2, one barrier per iter, counted vmcnt.
    for (int g = 0; g < nkb; g += 4) {
        const bool last = (g + 4 == nkb);
        // T = g+0
        stage(g + 2, (g + 2) & 3);
        asm volatile("s_waitcnt vmcnt(8)" ::: "memory");
        __builtin_amdgcn_s_barrier();
        compute(g * 64, g & 3);
        // T = g+1
        stage(g + 3, (g + 3) & 3);
        asm volatile("s_waitcnt vmcnt(8)" ::: "memory");
        __builtin_amdgcn_s_barrier();
        compute((g + 1) * 64, (g + 1) & 3);
        // T = g+2
        if (!last) {
            stage(g + 4, (g + 4) & 3);
            asm volatile("s_waitcnt vmcnt(8)" ::: "memory");
        } else {
            asm volatile("s_waitcnt vmcnt(4)" ::: "memory");
        }
        __builtin_amdgcn_s_barrier();
        compute((g + 2) * 64, (g + 2) & 3);
        // T = g+3
        if (!last) {
            stage(g + 5, (g + 5) & 3);
            asm volatile("s_waitcnt vmcnt(8)" ::: "memory");
        } else {
            asm volatile("s_waitcnt vmcnt(0)" ::: "memory");
        }
        __builtin_amdgcn_s_barrier();
        compute((g + 3) * 64, (g + 3) & 3);
    }

    // epilogue: out = acc / denom, staged via LDS (overlays K/V bufs)
    __syncthreads();   // all waves done reading pool
    unsigned short* Cs = pool;   // [256][128] = 64 KB
    #pragma unroll
    for (int mi = 0; mi < 2; ++mi) {
        #pragma unroll
        for (int r = 0; r < 4; ++r) {
            float dv = __shfl(accd[mi][r], lane & 48);  // col 0 lives in lane lg*16
            float rinv = 1.0f / dv;
            int rw = w * 32 + mi * 16 + lg * 4 + r;
            #pragma unroll
            for (int ni = 0; ni < 8; ++ni)
                Cs[rw * 128 + ni * 16 + lr] = f2bf(acc[mi][ni][r] * rinv);
        }
    }
    __syncthreads();
    #pragma unroll
    for (int i = 0; i < 8; ++i) {
        int ch = i * 512 + t;             // 4096 chunks of 8 shorts
        int row = ch >> 4, c8 = (ch & 15) * 8;
        *(uint4*)&O[(size_t)(q0 + row) * EDIM + h * HD + c8] = *(const uint4*)&Cs[row * 128 + c8];
    }
}

// ---------------------------------------------------------------- launch
extern "C" void kernel_launch(void* const* d_in, const int* in_sizes, int n_in,
                              void* d_out, int out_size, void* d_ws, size_t ws_size,
                              hipStream_t stream) {
    const float* x        = (const float*)d_in[0];
    const float* w_qkv    = (const float*)d_in[1];
    const float* w_out    = (const float*)d_in[2];
    const float* ln_scale = (const float*)d_in[3];
    const float* ln_bias  = (const float*)d_in[4];

    if (ws_size < 134217728u) return;  // need 128 MiB

    char* ws = (char*)d_ws;
    unsigned short* xb    = (unsigned short*)(ws);              // 16 MiB; reused as attnO
    unsigned short* wqkvT = (unsigned short*)(ws + 16777216);   // 24 MiB; reused as Qh
    unsigned short* woutT = (unsigned short*)(ws + 41943040);   //  8 MiB
    unsigned short* proj  = (unsigned short*)(ws + 50331648);   // 48 MiB
    unsigned short* Kh    = (unsigned short*)(ws + 100663296);  // 16 MiB
    unsigned short* Vt    = (unsigned short*)(ws + 117440512);  // 16 MiB
    unsigned short* Qh    = wqkvT;   // alias: w_qkvT dead after GEMM1
    unsigned short* attnO = xb;      // alias: xb dead after GEMM1

    k_convert_x<<<2048, 256, 0, stream>>>(x, xb, (N_SEQ * EDIM) / 4);
    k_transpose_f32_bf16<<<dim3(3 * EDIM / 64, EDIM / 64), 256, 0, stream>>>(w_qkv, wqkvT, EDIM, 3 * EDIM);
    k_transpose_f32_bf16<<<dim3(EDIM / 64, EDIM / 64), 256, 0, stream>>>(w_out, woutT, EDIM, EDIM);
    k_gemm_bt<0><<<dim3(3 * EDIM / 128, N_SEQ / 128), 256, 0, stream>>>(xb, wqkvT, proj, N_SEQ, 3 * EDIM, EDIM);
    k_ropeln<<<N_SEQ, 256, 0, stream>>>(proj, ln_scale, ln_bias, Qh, Kh);
    k_vtrans<<<dim3(N_SEQ / 64, NH), 256, 0, stream>>>(proj, Vt);
    k_attn<<<256, 512, 0, stream>>>(Qh, Kh, Vt, attnO);
    k_gemm_bt<1><<<dim3(EDIM / 128, N_SEQ / 128), 256, 0, stream>>>(attnO, woutT, (float*)d_out, N_SEQ, EDIM, EDIM);
}

// Round 10
// 317.014 us; speedup vs baseline: 1.0339x; 1.0339x over previous
//
#include <hip/hip_runtime.h>
#include <stdint.h>
#include <math.h>

// Problem constants
#define N_SEQ 4096
#define EDIM  2048
#define NH    16
#define HD    128

typedef __attribute__((ext_vector_type(8))) short bf16x8;
typedef __attribute__((ext_vector_type(4))) float f32x4;

#define AS1 __attribute__((address_space(1)))
#define AS3 __attribute__((address_space(3)))

__device__ __forceinline__ void gll16(const unsigned short* g, unsigned short* l) {
    __builtin_amdgcn_global_load_lds((const AS1 unsigned int*)g,
                                     (AS3 unsigned int*)l, 16, 0, 0);
}

__device__ __forceinline__ unsigned short f2bf(float f) {
    union { float f; unsigned u; } v; v.f = f;
    unsigned r = v.u + 0x7FFFu + ((v.u >> 16) & 1u);
    return (unsigned short)(r >> 16);
}
__device__ __forceinline__ float bf2f(unsigned short h) {
    union { unsigned u; float f; } v; v.u = ((unsigned)h) << 16;
    return v.f;
}

// ---------------------------------------------------------------- convert x
__global__ void k_convert_x(const float* __restrict__ x,
                            unsigned short* __restrict__ xb, int n4) {
    int i = blockIdx.x * blockDim.x + threadIdx.x;
    int stride = gridDim.x * blockDim.x;
    for (; i < n4; i += stride) {
        float4 v = ((const float4*)x)[i];
        ushort4 o;
        o.x = f2bf(v.x); o.y = f2bf(v.y); o.z = f2bf(v.z); o.w = f2bf(v.w);
        ((ushort4*)xb)[i] = o;
    }
}

// ---------------------------------------------- transpose f32 (RxC) -> bf16 (CxR)
__global__ void k_transpose_f32_bf16(const float* __restrict__ in,
                                     unsigned short* __restrict__ out,
                                     int R, int C) {
    __shared__ unsigned short Ls[64][68];
    const int c0 = blockIdx.x * 64, r0 = blockIdx.y * 64;
    const int t = threadIdx.x;
    #pragma unroll
    for (int i = 0; i < 4; ++i) {
        int ch = i * 256 + t;              // 1024 float4 chunks
        int r = ch >> 4, c4 = (ch & 15) * 4;
        float4 v = *(const float4*)&in[(size_t)(r0 + r) * C + c0 + c4];
        ushort4 o;
        o.x = f2bf(v.x); o.y = f2bf(v.y); o.z = f2bf(v.z); o.w = f2bf(v.w);
        *(ushort4*)&Ls[r][c4] = o;
    }
    __syncthreads();
    #pragma unroll
    for (int i = 0; i < 2; ++i) {
        int ch = i * 256 + t;              // 512 chunks of 8 bf16
        int rr = ch >> 3, c8 = (ch & 7) * 8;
        unsigned short vals[8];
        #pragma unroll
        for (int j = 0; j < 8; ++j) vals[j] = Ls[c8 + j][rr];
        uint4 pk;
        pk.x = (unsigned)vals[0] | ((unsigned)vals[1] << 16);
        pk.y = (unsigned)vals[2] | ((unsigned)vals[3] << 16);
        pk.z = (unsigned)vals[4] | ((unsigned)vals[5] << 16);
        pk.w = (unsigned)vals[6] | ((unsigned)vals[7] << 16);
        *(uint4*)&out[(size_t)(c0 + rr) * R + r0 + c8] = pk;
    }
}

// ---------------------------------------------------------------- bt GEMM
// C[M,N] = A[M,K] * Bt[N,K]^T  (bf16 in, f32 acc, bf16 or f32 out)
template<int F32OUT>
__launch_bounds__(256, 2)
__global__ void k_gemm_bt(const unsigned short* __restrict__ A,
                          const unsigned short* __restrict__ Bt,
                          void* __restrict__ C,
                          int M, int N, int K) {
    __shared__ unsigned short sh[2 * 128 * 64];   // As | Bs, linear [128][64]
    unsigned short* As = sh;
    unsigned short* Bs = sh + 128 * 64;

    const int t = threadIdx.x;
    const int wave = t >> 6, lane = t & 63;
    const int wm = wave >> 1, wn = wave & 1;
    const int lg = lane >> 4, lr = lane & 15;

    // XCD-aware bijective swizzle (nwg % 8 == 0 for all our grids)
    const int nbx = gridDim.x;
    const int nwg = nbx * gridDim.y;
    int bid = blockIdx.y * nbx + blockIdx.x;
    int swz = (bid & 7) * (nwg >> 3) + (bid >> 3);
    const int m0 = (swz / nbx) * 128;
    const int n0 = (swz % nbx) * 128;

    const unsigned short* aptr = A  + (size_t)m0 * K;
    const unsigned short* bptr = Bt + (size_t)n0 * K;

    f32x4 acc[4][4];
    #pragma unroll
    for (int i = 0; i < 4; ++i)
        #pragma unroll
        for (int j = 0; j < 4; ++j) acc[i][j] = f32x4{0.f, 0.f, 0.f, 0.f};

    // per-thread staging geometry (loop-invariant)
    int schr[4], srow[4], scb[4];
    #pragma unroll
    for (int i = 0; i < 4; ++i) {
        int ch = (i * 4 + wave) * 64 + lane;   // 0..1023, wave-uniform base + lane
        schr[i] = ch;
        srow[i] = ch >> 3;
        scb[i]  = (ch & 7) ^ ((ch >> 3) & 7);  // inverse-swizzled source col-block
    }

    const int nkb = K >> 6;
    for (int kb = 0; kb < nkb; ++kb) {
        __syncthreads();   // previous iter's ds_reads done before overwrite
        #pragma unroll
        for (int i = 0; i < 4; ++i) {
            const size_t goff = (size_t)srow[i] * K + (size_t)kb * 64 + scb[i] * 8;
            gll16(&aptr[goff], &As[schr[i] * 8]);
            gll16(&bptr[goff], &Bs[schr[i] * 8]);
        }
        __syncthreads();   // drains vmcnt+lgkm (compiler-inserted before barrier)

        #pragma unroll
        for (int kk = 0; kk < 2; ++kk) {
            bf16x8 af[4], bf[4];
            const int cbx = ((kk * 4 + lg) ^ (lr & 7)) * 8;  // swizzled read col
            #pragma unroll
            for (int i = 0; i < 4; ++i) {
                af[i] = *(const bf16x8*)&As[(wm * 64 + i * 16 + lr) * 64 + cbx];
                bf[i] = *(const bf16x8*)&Bs[(wn * 64 + i * 16 + lr) * 64 + cbx];
            }
            #pragma unroll
            for (int i = 0; i < 4; ++i)
                #pragma unroll
                for (int j = 0; j < 4; ++j)
                    acc[i][j] = __builtin_amdgcn_mfma_f32_16x16x32_bf16(af[i], bf[j], acc[i][j], 0, 0, 0);
        }
    }

    if (F32OUT) {
        #pragma unroll
        for (int i = 0; i < 4; ++i) {
            int row0 = m0 + wm * 64 + i * 16 + lg * 4;
            #pragma unroll
            for (int j = 0; j < 4; ++j) {
                int col = n0 + wn * 64 + j * 16 + lr;
                #pragma unroll
                for (int r = 0; r < 4; ++r)
                    ((float*)C)[(size_t)(row0 + r) * N + col] = acc[i][j][r];
            }
        }
    } else {
        // stage bf16 C-tile in LDS, write out coalesced uint4 rows
        __syncthreads();
        unsigned short* Cs = sh;     // [128][128]
        #pragma unroll
        for (int i = 0; i < 4; ++i) {
            #pragma unroll
            for (int j = 0; j < 4; ++j) {
                int col = wn * 64 + j * 16 + lr;
                #pragma unroll
                for (int r = 0; r < 4; ++r)
                    Cs[(wm * 64 + i * 16 + lg * 4 + r) * 128 + col] = f2bf(acc[i][j][r]);
            }
        }
        __syncthreads();
        #pragma unroll
        for (int i = 0; i < 8; ++i) {
            int ch = i * 256 + t;             // 2048 chunks of 8 shorts
            int row = ch >> 4, c8 = (ch & 15) * 8;
            *(uint4*)&((unsigned short*)C)[(size_t)(m0 + row) * N + n0 + c8] =
                *(const uint4*)&Cs[row * 128 + c8];
        }
    }
}

// ------------------------------------------------------- RoPE + LayerNorm (q,k)
__global__ void k_ropeln(const unsigned short* __restrict__ proj,
                         const float* __restrict__ ln_scale,
                         const float* __restrict__ ln_bias,
                         unsigned short* __restrict__ Qh,
                         unsigned short* __restrict__ Kh) {
    const int n = blockIdx.x;
    const int wave = threadIdx.x >> 6, lane = threadIdx.x & 63;
    float inv = expf(-((float)(2 * lane) / 128.0f) * 9.210340371976184f);
    float ang = (float)n * inv;
    float c = cosf(ang), s = sinf(ang);
    const float sc1 = ln_scale[lane], sc2 = ln_scale[lane + 64];
    const float b1 = ln_bias[lane],  b2 = ln_bias[lane + 64];

    for (int r = wave; r < 32; r += 4) {
        int h = r >> 1, qk = r & 1;
        const unsigned short* src = proj + (size_t)n * (3 * EDIM) + qk * EDIM + h * HD;
        float x1 = bf2f(src[lane]), x2 = bf2f(src[lane + 64]);
        float o1 = x1 * c - x2 * s;
        float o2 = x1 * s + x2 * c;
        float sum = o1 + o2, sq = o1 * o1 + o2 * o2;
        #pragma unroll
        for (int d = 1; d < 64; d <<= 1) {
            sum += __shfl_xor(sum, d);
            sq  += __shfl_xor(sq, d);
        }
        float mean = sum * (1.0f / 128.0f);
        float var = sq * (1.0f / 128.0f) - mean * mean;
        float rstd = rsqrtf(var + 1e-5f);
        float y1 = (o1 - mean) * rstd * sc1 + b1;
        float y2 = (o2 - mean) * rstd * sc2 + b2;
        unsigned short* dst = (qk ? Kh : Qh) + ((size_t)h * N_SEQ + n) * HD;
        dst[lane]      = f2bf(y1);
        dst[lane + 64] = f2bf(y2);
    }
}

// ---------------------------------------------------- V transpose: [n][d] -> [d][n]
// Writes Vt with the PV k-permutation baked into each 64-key tile:
// tile position p*8+i  <-  k = 32*(p>>2) + 16*(i>>2) + 4*(p&3) + (i&3)
// so attn's V B-fragment (s2,lg) is ONE contiguous b128 chunk c = s2*4+lg.
__global__ void k_vtrans(const unsigned short* __restrict__ proj,
                         unsigned short* __restrict__ Vt) {
    __shared__ unsigned short Ls[64][136];
    const int h = blockIdx.y;
    const int n0 = blockIdx.x * 64;
    const int t = threadIdx.x;
    #pragma unroll
    for (int i = 0; i < 4; ++i) {
        int ch = i * 256 + t;
        int r = ch >> 4, d0 = (ch & 15) * 8;
        uint4 v = *(const uint4*)&proj[(size_t)(n0 + r) * (3 * EDIM) + 2 * EDIM + h * HD + d0];
        *(uint4*)&Ls[r][d0] = v;
    }
    __syncthreads();
    #pragma unroll
    for (int i = 0; i < 4; ++i) {
        int ch = i * 256 + t;
        int d = ch >> 3, p = ch & 7;
        unsigned short vals[8];
        #pragma unroll
        for (int j = 0; j < 8; ++j) {
            int ko = 32 * (p >> 2) + 16 * (j >> 2) + 4 * (p & 3) + (j & 3);
            vals[j] = Ls[ko][d];
        }
        uint4 pk;
        pk.x = (unsigned)vals[0] | ((unsigned)vals[1] << 16);
        pk.y = (unsigned)vals[2] | ((unsigned)vals[3] << 16);
        pk.z = (unsigned)vals[4] | ((unsigned)vals[5] << 16);
        pk.w = (unsigned)vals[6] | ((unsigned)vals[7] << 16);
        *(uint4*)&Vt[((size_t)h * HD + d) * N_SEQ + n0 + p * 8] = pk;
    }
}

// ------------------------------------------------------- polynomial attention
// v9: round-8 core (swapped QK^T, in-register P, permuted-V b128 reads,
// unroll-2 dbuf, vmcnt(8)) + K-SPLIT load balance: polynomial attn is a pure
// sum (no max/rescale), so heavy tiles (qb>=16) split into two k-chunks of
// <=32 iters writing f32 partials (num,den); light tiles (qb<=15) write O
// directly. 768 blocks -> work-conserving 2-blocks/CU; critical chain halved.
__launch_bounds__(256, 2)
__global__ void k_attn(const unsigned short* __restrict__ Qh,
                       const unsigned short* __restrict__ Kh,
                       const unsigned short* __restrict__ Vt,
                       unsigned short* __restrict__ O,
                       float* __restrict__ PN,
                       float* __restrict__ PD) {
    // pool: Ks[2][64][128] | Vts[2][128][64]  = 64 KB (epilogue reuses as Cs)
    __shared__ unsigned short pool[4 * 8192];

    const int t = threadIdx.x;
    const int w = t >> 6, lane = t & 63;
    const int lg = lane >> 4, lr = lane & 15;

    // block decode (b&7 = XCD = h>>1 keeps each head pair's K/V in one L2):
    //  b in [0,512): split chunks of heavy tiles qb=16..31 (17-32 iters each)
    //  b in [512,768): full light tiles qb=0..15
    const int b = blockIdx.x;
    int h, qb, c_lo, c_hi, pidx = 0, chunk = 0;
    bool partial;
    if (b < 512) {
        int ti = b & 255;
        chunk = b >> 8;
        h  = (ti & 7) * 2 + ((ti >> 3) & 1);
        qb = 31 - ((ti >> 4) & 15);
        int nkb = 2 * qb + 2;
        int c0 = (qb + 2) & ~1;          // even split point
        c_lo = chunk ? c0 : 0;
        c_hi = chunk ? nkb : c0;
        partial = true;
        pidx = ti;
    } else {
        int idx = b - 512;
        h  = (idx & 7) * 2 + ((idx >> 3) & 1);
        qb = 15 - (idx >> 4);
        c_lo = 0;
        c_hi = 2 * qb + 2;
        partial = false;
    }
    const int q0 = qb * 128;
    const int qbase = q0 + w * 32;   // this wave's first q-row

    // Q fragments in registers (wave's 32 queries x 128 d)
    bf16x8 qf[2][4];
    #pragma unroll
    for (int mi = 0; mi < 2; ++mi)
        #pragma unroll
        for (int kk = 0; kk < 4; ++kk)
            qf[mi][kk] = *(const bf16x8*)&Qh[((size_t)h * N_SEQ + qbase + mi * 16 + lr) * HD + kk * 32 + lg * 8];

    f32x4 acc[2][8];
    #pragma unroll
    for (int i = 0; i < 2; ++i)
        #pragma unroll
        for (int j = 0; j < 8; ++j) acc[i][j] = f32x4{0.f, 0.f, 0.f, 0.f};
    f32x4 accd[2];
    accd[0] = f32x4{0.f, 0.f, 0.f, 0.f};
    accd[1] = f32x4{0.f, 0.f, 0.f, 0.f};

    // ones B-fragment: row-sum lands in output col 0 (k-permutation-invariant)
    bf16x8 onesf;
    {
        short ov = (lr == 0) ? (short)0x3F80 : (short)0;
        #pragma unroll
        for (int j = 0; j < 8; ++j) onesf[j] = ov;
    }

    // staging geometry: K 1024 chunks (4/thread), V 1024 chunks (4/thread).
    int kch[4], vch[4];
    const unsigned short* kg[4];
    const unsigned short* vg[4];
    #pragma unroll
    for (int i = 0; i < 4; ++i) {
        int ch = i * 256 + t;
        kch[i] = ch;
        int r = ch >> 4, p = ch & 15;
        int csrc = (p & 8) | ((p ^ r) & 7);
        kg[i] = Kh + ((size_t)h * N_SEQ + r) * HD + csrc * 8 + (size_t)c_lo * 64 * HD;
    }
    #pragma unroll
    for (int i = 0; i < 4; ++i) {
        int ch = i * 256 + t;
        vch[i] = ch;
        int d = ch >> 3, p2 = ch & 7;
        int c2src = (p2 ^ d) & 7;
        vg[i] = Vt + ((size_t)h * HD + d) * N_SEQ + c2src * 8 + (size_t)c_lo * 64;
    }

    union U8 { unsigned u[4]; bf16x8 v; };

    auto stage = [&](unsigned short* Kn, unsigned short* Vn) {
        #pragma unroll
        for (int i = 0; i < 4; ++i) { gll16(kg[i], Kn + kch[i] * 8); kg[i] += 64 * HD; }
        #pragma unroll
        for (int i = 0; i < 4; ++i) { gll16(vg[i], Vn + vch[i] * 8); vg[i] += 64; }
    };

    auto compute = [&](int k0, const unsigned short* Kc, const unsigned short* Vc) {
        // ---- S^T = K Q^T (swapped): lane holds S[k = 16nj+4lg+r][q = 16mi+lr]
        f32x4 sa[2][4];
        #pragma unroll
        for (int i = 0; i < 2; ++i)
            #pragma unroll
            for (int j = 0; j < 4; ++j) sa[i][j] = f32x4{0.f, 0.f, 0.f, 0.f};
        #pragma unroll
        for (int nn = 0; nn < 2; ++nn) {
            bf16x8 kf[2][4];
            #pragma unroll
            for (int nj = 0; nj < 2; ++nj)
                #pragma unroll
                for (int kk = 0; kk < 4; ++kk) {
                    int row = (nn * 2 + nj) * 16 + lr;
                    int c = kk * 4 + lg;
                    int cs = (c & 8) | ((c ^ row) & 7);
                    kf[nj][kk] = *(const bf16x8*)&Kc[row * 128 + cs * 8];
                }
            __builtin_amdgcn_s_setprio(1);
            #pragma unroll
            for (int kk = 0; kk < 4; ++kk)
                #pragma unroll
                for (int nj = 0; nj < 2; ++nj)
                    #pragma unroll
                    for (int mi = 0; mi < 2; ++mi)
                        sa[mi][nn * 2 + nj] = __builtin_amdgcn_mfma_f32_16x16x32_bf16(
                            kf[nj][kk], qf[mi][kk], sa[mi][nn * 2 + nj], 0, 0, 0);
            __builtin_amdgcn_s_setprio(0);
        }

        // ---- mask + ^4 + pack to bf16 pairs, all in registers.
        unsigned wreg[2][4][2];
        const bool nomask = (k0 + 63 <= qbase);
        #pragma unroll
        for (int mi = 0; mi < 2; ++mi)
            #pragma unroll
            for (int nj = 0; nj < 4; ++nj) {
                float p[4];
                #pragma unroll
                for (int r = 0; r < 4; ++r) {
                    float sv = sa[mi][nj][r];
                    float t2 = sv * sv;
                    p[r] = t2 * t2;
                    if (!nomask) {
                        int gk = k0 + nj * 16 + lg * 4 + r;
                        int gq = qbase + mi * 16 + lr;
                        p[r] = (gk <= gq) ? p[r] : 0.0f;
                    }
                }
                asm("v_cvt_pk_bf16_f32 %0, %1, %2" : "=v"(wreg[mi][nj][0]) : "v"(p[0]), "v"(p[1]));
                asm("v_cvt_pk_bf16_f32 %0, %1, %2" : "=v"(wreg[mi][nj][1]) : "v"(p[2]), "v"(p[3]));
            }

        // ---- O += P V, denom += P * ones.  Vt's baked tile permutation makes
        // each B-frag one b128 at chunk c = s2*4+lg (XOR-swizzled).
        #pragma unroll
        for (int s2 = 0; s2 < 2; ++s2) {
            bf16x8 pa[2];
            #pragma unroll
            for (int mi = 0; mi < 2; ++mi) {
                U8 u;
                u.u[0] = wreg[mi][2 * s2][0];
                u.u[1] = wreg[mi][2 * s2][1];
                u.u[2] = wreg[mi][2 * s2 + 1][0];
                u.u[3] = wreg[mi][2 * s2 + 1][1];
                pa[mi] = u.v;
            }
            __builtin_amdgcn_s_setprio(1);
            #pragma unroll
            for (int ni = 0; ni < 8; ++ni) {
                int d = ni * 16 + lr;
                int cs = ((s2 * 4 + lg) ^ (d & 7)) & 7;
                bf16x8 vf = *(const bf16x8*)&Vc[d * 64 + cs * 8];
                #pragma unroll
                for (int mi = 0; mi < 2; ++mi)
                    acc[mi][ni] = __builtin_amdgcn_mfma_f32_16x16x32_bf16(pa[mi], vf, acc[mi][ni], 0, 0, 0);
            }
            #pragma unroll
            for (int mi = 0; mi < 2; ++mi)
                accd[mi] = __builtin_amdgcn_mfma_f32_16x16x32_bf16(pa[mi], onesf, accd[mi], 0, 0, 0);
            __builtin_amdgcn_s_setprio(0);
        }
    };

    // prologue: stage tile c_lo into buf 0 (8 loads/thread)
    stage(pool, pool + 16384);

    for (int kb = c_lo; kb < c_hi; kb += 2) {   // (c_hi - c_lo) always even
        // ---- A: prefetch tile kb+1 -> buf1, compute tile kb from buf0
        stage(pool + 8192, pool + 16384 + 8192);
        asm volatile("s_waitcnt vmcnt(8)" ::: "memory");
        __builtin_amdgcn_s_barrier();
        compute(kb * 64, pool, pool + 16384);
        __builtin_amdgcn_s_barrier();
        // ---- B: prefetch tile kb+2 -> buf0 (unless last), compute tile kb+1
        if (kb + 2 < c_hi) {
            stage(pool, pool + 16384);
            asm volatile("s_waitcnt vmcnt(8)" ::: "memory");
        } else {
            asm volatile("s_waitcnt vmcnt(0)" ::: "memory");
        }
        __builtin_amdgcn_s_barrier();
        compute((kb + 1) * 64, pool + 8192, pool + 16384 + 8192);
        __builtin_amdgcn_s_barrier();
    }

    if (partial) {
        // store raw f32 partials: num [128][128], den [128]
        float* pn = PN + (size_t)(pidx * 2 + chunk) * 16384;
        float* pd = PD + (size_t)(pidx * 2 + chunk) * 128;
        #pragma unroll
        for (int mi = 0; mi < 2; ++mi) {
            #pragma unroll
            for (int r = 0; r < 4; ++r) {
                int rw = w * 32 + mi * 16 + lg * 4 + r;
                if (lr == 0) pd[rw] = accd[mi][r];
                #pragma unroll
                for (int ni = 0; ni < 8; ++ni)
                    pn[rw * 128 + ni * 16 + lr] = acc[mi][ni][r];
            }
        }
    } else {
        // epilogue: out = acc / denom, staged via LDS (overlays K/V bufs)
        unsigned short* Cs = pool;   // [128][128] = 32 KB
        #pragma unroll
        for (int mi = 0; mi < 2; ++mi) {
            #pragma unroll
            for (int r = 0; r < 4; ++r) {
                float dv = __shfl(accd[mi][r], lane & 48);  // col 0 lives in lane lg*16
                float rinv = 1.0f / dv;
                int rw = w * 32 + mi * 16 + lg * 4 + r;
                #pragma unroll
                for (int ni = 0; ni < 8; ++ni)
                    Cs[rw * 128 + ni * 16 + lr] = f2bf(acc[mi][ni][r] * rinv);
            }
        }
        __syncthreads();
        #pragma unroll
        for (int i = 0; i < 8; ++i) {
            int ch = i * 256 + t;
            int row = ch >> 4, c8 = (ch & 15) * 8;
            *(uint4*)&O[(size_t)(q0 + row) * EDIM + h * HD + c8] = *(const uint4*)&Cs[row * 128 + c8];
        }
    }
}

// ------------------------------------------------- combine split-tile partials
// out = (num0+num1) / (den0+den1). 256 blocks (one per split tile) x 256 thr.
__global__ void k_combine(const float* __restrict__ PN,
                          const float* __restrict__ PD,
                          unsigned short* __restrict__ O) {
    const int ti = blockIdx.x;
    const int h  = (ti & 7) * 2 + ((ti >> 3) & 1);
    const int qb = 31 - ((ti >> 4) & 15);
    const int q0 = qb * 128;
    const int t = threadIdx.x;
    const int r = t >> 1, half = t & 1;

    const float* n0 = PN + (size_t)(ti * 2) * 16384 + r * 128 + half * 64;
    const float* n1 = n0 + 16384;
    float den = PD[(size_t)(ti * 2) * 128 + r] + PD[(size_t)(ti * 2 + 1) * 128 + r];
    float rinv = 1.0f / den;

    unsigned short vals[64];
    #pragma unroll
    for (int c = 0; c < 64; c += 4) {
        float4 a = *(const float4*)&n0[c];
        float4 b = *(const float4*)&n1[c];
        vals[c + 0] = f2bf((a.x + b.x) * rinv);
        vals[c + 1] = f2bf((a.y + b.y) * rinv);
        vals[c + 2] = f2bf((a.z + b.z) * rinv);
        vals[c + 3] = f2bf((a.w + b.w) * rinv);
    }
    unsigned short* dst = O + (size_t)(q0 + r) * EDIM + h * HD + half * 64;
    #pragma unroll
    for (int i = 0; i < 8; ++i)
        *(uint4*)&dst[i * 8] = *(const uint4*)&vals[i * 8];
}

// ---------------------------------------------------------------- launch
extern "C" void kernel_launch(void* const* d_in, const int* in_sizes, int n_in,
                              void* d_out, int out_size, void* d_ws, size_t ws_size,
                              hipStream_t stream) {
    const float* x        = (const float*)d_in[0];
    const float* w_qkv    = (const float*)d_in[1];
    const float* w_out    = (const float*)d_in[2];
    const float* ln_scale = (const float*)d_in[3];
    const float* ln_bias  = (const float*)d_in[4];

    if (ws_size < 134217728u) return;  // need 128 MiB

    char* ws = (char*)d_ws;
    unsigned short* xb    = (unsigned short*)(ws);              // 16 MiB; reused as attnO
    unsigned short* wqkvT = (unsigned short*)(ws + 16777216);   // 24 MiB; reused as Qh
    unsigned short* woutT = (unsigned short*)(ws + 41943040);   //  8 MiB
    unsigned short* proj  = (unsigned short*)(ws + 50331648);   // 48 MiB; reused as PN/PD
    unsigned short* Kh    = (unsigned short*)(ws + 100663296);  // 16 MiB
    unsigned short* Vt    = (unsigned short*)(ws + 117440512);  // 16 MiB
    unsigned short* Qh    = wqkvT;   // alias: w_qkvT dead after GEMM1
    unsigned short* attnO = xb;      // alias: xb dead after GEMM1
    float* PN = (float*)(ws + 50331648);            // 32 MiB partial nums
    float* PD = (float*)(ws + 50331648 + 33554432); // 256 KiB partial dens

    k_convert_x<<<2048, 256, 0, stream>>>(x, xb, (N_SEQ * EDIM) / 4);
    k_transpose_f32_bf16<<<dim3(3 * EDIM / 64, EDIM / 64), 256, 0, stream>>>(w_qkv, wqkvT, EDIM, 3 * EDIM);
    k_transpose_f32_bf16<<<dim3(EDIM / 64, EDIM / 64), 256, 0, stream>>>(w_out, woutT, EDIM, EDIM);
    k_gemm_bt<0><<<dim3(3 * EDIM / 128, N_SEQ / 128), 256, 0, stream>>>(xb, wqkvT, proj, N_SEQ, 3 * EDIM, EDIM);
    k_ropeln<<<N_SEQ, 256, 0, stream>>>(proj, ln_scale, ln_bias, Qh, Kh);
    k_vtrans<<<dim3(N_SEQ / 64, NH), 256, 0, stream>>>(proj, Vt);
    k_attn<<<768, 256, 0, stream>>>(Qh, Kh, Vt, attnO, PN, PD);
    k_combine<<<256, 256, 0, stream>>>(PN, PD, attnO);
    k_gemm_bt<1><<<dim3(EDIM / 128, N_SEQ / 128), 256, 0, stream>>>(attnO, woutT, (float*)d_out, N_SEQ, EDIM, EDIM);
}

// Round 11
// 303.216 us; speedup vs baseline: 1.0809x; 1.0455x over previous
//
#include <hip/hip_runtime.h>
#include <stdint.h>
#include <math.h>

// Problem constants
#define N_SEQ 4096
#define EDIM  2048
#define NH    16
#define HD    128

typedef __attribute__((ext_vector_type(8))) short bf16x8;
typedef __attribute__((ext_vector_type(4))) float f32x4;

#define AS1 __attribute__((address_space(1)))
#define AS3 __attribute__((address_space(3)))

__device__ __forceinline__ void gll16(const unsigned short* g, unsigned short* l) {
    __builtin_amdgcn_global_load_lds((const AS1 unsigned int*)g,
                                     (AS3 unsigned int*)l, 16, 0, 0);
}

__device__ __forceinline__ unsigned short f2bf(float f) {
    union { float f; unsigned u; } v; v.f = f;
    unsigned r = v.u + 0x7FFFu + ((v.u >> 16) & 1u);
    return (unsigned short)(r >> 16);
}
__device__ __forceinline__ float bf2f(unsigned short h) {
    union { unsigned u; float f; } v; v.u = ((unsigned)h) << 16;
    return v.f;
}

// ---------------------------------------------------------------- convert x
__global__ void k_convert_x(const float* __restrict__ x,
                            unsigned short* __restrict__ xb, int n4) {
    int i = blockIdx.x * blockDim.x + threadIdx.x;
    int stride = gridDim.x * blockDim.x;
    for (; i < n4; i += stride) {
        float4 v = ((const float4*)x)[i];
        ushort4 o;
        o.x = f2bf(v.x); o.y = f2bf(v.y); o.z = f2bf(v.z); o.w = f2bf(v.w);
        ((ushort4*)xb)[i] = o;
    }
}

// ---------------------------------------------- transpose f32 (RxC) -> bf16 (CxR)
__global__ void k_transpose_f32_bf16(const float* __restrict__ in,
                                     unsigned short* __restrict__ out,
                                     int R, int C) {
    __shared__ unsigned short Ls[64][68];
    const int c0 = blockIdx.x * 64, r0 = blockIdx.y * 64;
    const int t = threadIdx.x;
    #pragma unroll
    for (int i = 0; i < 4; ++i) {
        int ch = i * 256 + t;              // 1024 float4 chunks
        int r = ch >> 4, c4 = (ch & 15) * 4;
        float4 v = *(const float4*)&in[(size_t)(r0 + r) * C + c0 + c4];
        ushort4 o;
        o.x = f2bf(v.x); o.y = f2bf(v.y); o.z = f2bf(v.z); o.w = f2bf(v.w);
        *(ushort4*)&Ls[r][c4] = o;
    }
    __syncthreads();
    #pragma unroll
    for (int i = 0; i < 2; ++i) {
        int ch = i * 256 + t;              // 512 chunks of 8 bf16
        int rr = ch >> 3, c8 = (ch & 7) * 8;
        unsigned short vals[8];
        #pragma unroll
        for (int j = 0; j < 8; ++j) vals[j] = Ls[c8 + j][rr];
        uint4 pk;
        pk.x = (unsigned)vals[0] | ((unsigned)vals[1] << 16);
        pk.y = (unsigned)vals[2] | ((unsigned)vals[3] << 16);
        pk.z = (unsigned)vals[4] | ((unsigned)vals[5] << 16);
        pk.w = (unsigned)vals[6] | ((unsigned)vals[7] << 16);
        *(uint4*)&out[(size_t)(c0 + rr) * R + r0 + c8] = pk;
    }
}

// ---------------------------------------------------------------- bt GEMM (m97)
// kept for gemm2 (f32 out, 128x128 tile -> 512 blocks = full occupancy)
template<int F32OUT>
__launch_bounds__(256, 2)
__global__ void k_gemm_bt(const unsigned short* __restrict__ A,
                          const unsigned short* __restrict__ Bt,
                          void* __restrict__ C,
                          int M, int N, int K) {
    __shared__ unsigned short sh[2 * 128 * 64];   // As | Bs, linear [128][64]
    unsigned short* As = sh;
    unsigned short* Bs = sh + 128 * 64;

    const int t = threadIdx.x;
    const int wave = t >> 6, lane = t & 63;
    const int wm = wave >> 1, wn = wave & 1;
    const int lg = lane >> 4, lr = lane & 15;

    const int nbx = gridDim.x;
    const int nwg = nbx * gridDim.y;
    int bid = blockIdx.y * nbx + blockIdx.x;
    int swz = (bid & 7) * (nwg >> 3) + (bid >> 3);
    const int m0 = (swz / nbx) * 128;
    const int n0 = (swz % nbx) * 128;

    const unsigned short* aptr = A  + (size_t)m0 * K;
    const unsigned short* bptr = Bt + (size_t)n0 * K;

    f32x4 acc[4][4];
    #pragma unroll
    for (int i = 0; i < 4; ++i)
        #pragma unroll
        for (int j = 0; j < 4; ++j) acc[i][j] = f32x4{0.f, 0.f, 0.f, 0.f};

    int schr[4], srow[4], scb[4];
    #pragma unroll
    for (int i = 0; i < 4; ++i) {
        int ch = (i * 4 + wave) * 64 + lane;
        schr[i] = ch;
        srow[i] = ch >> 3;
        scb[i]  = (ch & 7) ^ ((ch >> 3) & 7);
    }

    const int nkb = K >> 6;
    for (int kb = 0; kb < nkb; ++kb) {
        __syncthreads();
        #pragma unroll
        for (int i = 0; i < 4; ++i) {
            const size_t goff = (size_t)srow[i] * K + (size_t)kb * 64 + scb[i] * 8;
            gll16(&aptr[goff], &As[schr[i] * 8]);
            gll16(&bptr[goff], &Bs[schr[i] * 8]);
        }
        __syncthreads();

        #pragma unroll
        for (int kk = 0; kk < 2; ++kk) {
            bf16x8 af[4], bf[4];
            const int cbx = ((kk * 4 + lg) ^ (lr & 7)) * 8;
            #pragma unroll
            for (int i = 0; i < 4; ++i) {
                af[i] = *(const bf16x8*)&As[(wm * 64 + i * 16 + lr) * 64 + cbx];
                bf[i] = *(const bf16x8*)&Bs[(wn * 64 + i * 16 + lr) * 64 + cbx];
            }
            #pragma unroll
            for (int i = 0; i < 4; ++i)
                #pragma unroll
                for (int j = 0; j < 4; ++j)
                    acc[i][j] = __builtin_amdgcn_mfma_f32_16x16x32_bf16(af[i], bf[j], acc[i][j], 0, 0, 0);
        }
    }

    if (F32OUT) {
        #pragma unroll
        for (int i = 0; i < 4; ++i) {
            int row0 = m0 + wm * 64 + i * 16 + lg * 4;
            #pragma unroll
            for (int j = 0; j < 4; ++j) {
                int col = n0 + wn * 64 + j * 16 + lr;
                #pragma unroll
                for (int r = 0; r < 4; ++r)
                    ((float*)C)[(size_t)(row0 + r) * N + col] = acc[i][j][r];
            }
        }
    } else {
        __syncthreads();
        unsigned short* Cs = sh;     // [128][128]
        #pragma unroll
        for (int i = 0; i < 4; ++i) {
            #pragma unroll
            for (int j = 0; j < 4; ++j) {
                int col = wn * 64 + j * 16 + lr;
                #pragma unroll
                for (int r = 0; r < 4; ++r)
                    Cs[(wm * 64 + i * 16 + lg * 4 + r) * 128 + col] = f2bf(acc[i][j][r]);
            }
        }
        __syncthreads();
        #pragma unroll
        for (int i = 0; i < 8; ++i) {
            int ch = i * 256 + t;
            int row = ch >> 4, c8 = (ch & 15) * 8;
            *(uint4*)&((unsigned short*)C)[(size_t)(m0 + row) * N + n0 + c8] =
                *(const uint4*)&Cs[row * 128 + c8];
        }
    }
}

// ---------------------------------------------------- 256x256 8-phase GEMM (gemm1)
// C[M,N] = A[M,K]*Bt[N,K]^T, bf16 in, f32 acc, bf16 out. m201-style:
// BM=BN=256, BK=64, 8 waves (2Mx4N, 128x64/wave), 128 KB LDS = 2 bufs x
// [A0|A1|B0|B1] 16KB half-tile regions. Phases = m-half x k-step; ds_reads
// 8/8/4/4; 16 MFMA/phase under setprio; stage 1 half-tile/phase in order
// A0(t+1),A1(t+1),B0(t+2),B1(t+2) | A0(t+2),A1(t+2),B0(t+3),B1(t+3);
// counted vmcnt(4) ONLY at phases 4/8 (A(t+1) landed, B(t+2) in flight).
// Region handoff verified: B-regions free after ph2, A-regions after ph4.
__launch_bounds__(512, 2)
__global__ void k_gemm256_bt(const unsigned short* __restrict__ A,
                             const unsigned short* __restrict__ Bt,
                             unsigned short* __restrict__ C,
                             int M, int N, int K) {
    __shared__ unsigned short pool[65536];   // 128 KB

    const int tid = threadIdx.x;
    const int wave = tid >> 6, lane = tid & 63;
    const int wm = wave >> 2, wn = wave & 3;
    const int lg = lane >> 4, lr = lane & 15;

    const int nbx = gridDim.x;
    const int nwg = nbx * gridDim.y;
    int bid = blockIdx.y * nbx + blockIdx.x;
    int swz = (bid & 7) * (nwg >> 3) + (bid >> 3);
    const int m0 = (swz / nbx) * 256;
    const int n0 = (swz % nbx) * 256;

    // staging: half-tile = 128 rows x 8 col-chunks = 1024 chunks, 2/thread;
    // source col-chunk pre-swizzled (involution), LDS dest linear.
    int ach[2];
    const unsigned short *Asrc[2], *Bsrc[2];
    #pragma unroll
    for (int i = 0; i < 2; ++i) {
        int ch = i * 512 + tid;
        ach[i] = ch;
        int r = ch >> 3, p = ch & 7;
        int csrc = (p ^ (r & 7)) & 7;
        Asrc[i] = A  + (size_t)(m0 + r) * K + csrc * 8;
        Bsrc[i] = Bt + (size_t)(n0 + r) * K + csrc * 8;
    }

    f32x4 acc[8][4];
    #pragma unroll
    for (int i = 0; i < 8; ++i)
        #pragma unroll
        for (int j = 0; j < 4; ++j) acc[i][j] = f32x4{0.f, 0.f, 0.f, 0.f};

    auto stA = [&](int T, int b, int hf) {
        #pragma unroll
        for (int i = 0; i < 2; ++i)
            gll16(Asrc[i] + (size_t)hf * 128 * K + (size_t)T * 64,
                  pool + b * 32768 + hf * 8192 + ach[i] * 8);
    };
    auto stB = [&](int T, int b, int hf) {
        #pragma unroll
        for (int i = 0; i < 2; ++i)
            gll16(Bsrc[i] + (size_t)hf * 128 * K + (size_t)T * 64,
                  pool + b * 32768 + 16384 + hf * 8192 + ach[i] * 8);
    };

    bf16x8 af[4], bf0[4], bf1[4];
    auto rdA = [&](int b, int mh, int ks) {
        const unsigned short* Ab = pool + b * 32768 + wm * 8192;
        const int cs = ((ks * 4 + lg) ^ (lr & 7)) & 7;
        #pragma unroll
        for (int j = 0; j < 4; ++j)
            af[j] = *(const bf16x8*)&Ab[((mh * 4 + j) * 16 + lr) * 64 + cs * 8];
    };
    auto rdB = [&](int b, int ks, bf16x8* dst) {
        const unsigned short* Bb = pool + b * 32768 + 16384 + (wn >> 1) * 8192;
        const int cs = ((ks * 4 + lg) ^ (lr & 7)) & 7;
        #pragma unroll
        for (int j = 0; j < 4; ++j)
            dst[j] = *(const bf16x8*)&Bb[((wn & 1) * 64 + j * 16 + lr) * 64 + cs * 8];
    };
    auto mm16 = [&](int mh, const bf16x8* bfr) {
        __builtin_amdgcn_s_setprio(1);
        #pragma unroll
        for (int j = 0; j < 4; ++j)
            #pragma unroll
            for (int n = 0; n < 4; ++n)
                acc[mh * 4 + j][n] = __builtin_amdgcn_mfma_f32_16x16x32_bf16(
                    af[j], bfr[n], acc[mh * 4 + j][n], 0, 0, 0);
        __builtin_amdgcn_s_setprio(0);
    };

    const int NT = K >> 6;   // 32, even

    // prologue: tile0 (all 4 halves) -> buf0; tile1 B halves -> buf1
    stA(0, 0, 0); stA(0, 0, 1); stB(0, 0, 0); stB(0, 0, 1);
    stB(1, 1, 0); stB(1, 1, 1);
    asm volatile("s_waitcnt vmcnt(0)" ::: "memory");
    __builtin_amdgcn_s_barrier();

    for (int t = 0; t < NT; t += 2) {
        const bool more = (t + 2 < NT);
        // ---- tile t (buf0) ----
        rdA(0, 0, 0); rdB(0, 0, bf0);          // ph1: 8 ds_reads
        stA(t + 1, 1, 0);
        __builtin_amdgcn_s_barrier();
        mm16(0, bf0);
        __builtin_amdgcn_s_barrier();
        rdA(0, 0, 1); rdB(0, 1, bf1);          // ph2: 8 ds_reads
        stA(t + 1, 1, 1);
        __builtin_amdgcn_s_barrier();
        mm16(0, bf1);
        __builtin_amdgcn_s_barrier();
        rdA(0, 1, 0);                          // ph3: 4 ds_reads (bf0 in regs)
        if (more) stB(t + 2, 0, 0);
        __builtin_amdgcn_s_barrier();
        mm16(1, bf0);
        __builtin_amdgcn_s_barrier();
        rdA(0, 1, 1);                          // ph4: 4 ds_reads
        if (more) { stB(t + 2, 0, 1); asm volatile("s_waitcnt vmcnt(4)" ::: "memory"); }
        else      { asm volatile("s_waitcnt vmcnt(0)" ::: "memory"); }
        __builtin_amdgcn_s_barrier();
        mm16(1, bf1);
        __builtin_amdgcn_s_barrier();
        // ---- tile t+1 (buf1) ----
        rdA(1, 0, 0); rdB(1, 0, bf0);          // ph5
        if (more) stA(t + 2, 0, 0);
        __builtin_amdgcn_s_barrier();
        mm16(0, bf0);
        __builtin_amdgcn_s_barrier();
        rdA(1, 0, 1); rdB(1, 1, bf1);          // ph6
        if (more) stA(t + 2, 0, 1);
        __builtin_amdgcn_s_barrier();
        mm16(0, bf1);
        __builtin_amdgcn_s_barrier();
        rdA(1, 1, 0);                          // ph7
        if (more) stB(t + 3, 1, 0);
        __builtin_amdgcn_s_barrier();
        mm16(1, bf0);
        __builtin_amdgcn_s_barrier();
        rdA(1, 1, 1);                          // ph8
        if (more) { stB(t + 3, 1, 1); asm volatile("s_waitcnt vmcnt(4)" ::: "memory"); }
        else      { asm volatile("s_waitcnt vmcnt(0)" ::: "memory"); }
        __builtin_amdgcn_s_barrier();
        mm16(1, bf1);
        __builtin_amdgcn_s_barrier();
    }

    // epilogue: stage bf16 C-tile in LDS (256x256 = full pool), coalesced out
    __syncthreads();
    unsigned short* Cs = pool;
    #pragma unroll
    for (int mj = 0; mj < 8; ++mj)
        #pragma unroll
        for (int nj = 0; nj < 4; ++nj)
            #pragma unroll
            for (int r = 0; r < 4; ++r)
                Cs[(wm * 128 + mj * 16 + lg * 4 + r) * 256 + wn * 64 + nj * 16 + lr] =
                    f2bf(acc[mj][nj][r]);
    __syncthreads();
    #pragma unroll
    for (int i = 0; i < 16; ++i) {
        int ch = i * 512 + tid;
        int row = ch >> 5, c8 = (ch & 31) * 8;
        *(uint4*)&C[(size_t)(m0 + row) * N + n0 + c8] = *(const uint4*)&Cs[row * 256 + c8];
    }
}

// ------------------------------------------------------- RoPE + LayerNorm (q,k)
__global__ void k_ropeln(const unsigned short* __restrict__ proj,
                         const float* __restrict__ ln_scale,
                         const float* __restrict__ ln_bias,
                         unsigned short* __restrict__ Qh,
                         unsigned short* __restrict__ Kh) {
    const int n = blockIdx.x;
    const int wave = threadIdx.x >> 6, lane = threadIdx.x & 63;
    float inv = expf(-((float)(2 * lane) / 128.0f) * 9.210340371976184f);
    float ang = (float)n * inv;
    float c = cosf(ang), s = sinf(ang);
    const float sc1 = ln_scale[lane], sc2 = ln_scale[lane + 64];
    const float b1 = ln_bias[lane],  b2 = ln_bias[lane + 64];

    for (int r = wave; r < 32; r += 4) {
        int h = r >> 1, qk = r & 1;
        const unsigned short* src = proj + (size_t)n * (3 * EDIM) + qk * EDIM + h * HD;
        float x1 = bf2f(src[lane]), x2 = bf2f(src[lane + 64]);
        float o1 = x1 * c - x2 * s;
        float o2 = x1 * s + x2 * c;
        float sum = o1 + o2, sq = o1 * o1 + o2 * o2;
        #pragma unroll
        for (int d = 1; d < 64; d <<= 1) {
            sum += __shfl_xor(sum, d);
            sq  += __shfl_xor(sq, d);
        }
        float mean = sum * (1.0f / 128.0f);
        float var = sq * (1.0f / 128.0f) - mean * mean;
        float rstd = rsqrtf(var + 1e-5f);
        float y1 = (o1 - mean) * rstd * sc1 + b1;
        float y2 = (o2 - mean) * rstd * sc2 + b2;
        unsigned short* dst = (qk ? Kh : Qh) + ((size_t)h * N_SEQ + n) * HD;
        dst[lane]      = f2bf(y1);
        dst[lane + 64] = f2bf(y2);
    }
}

// ---------------------------------------------------- V transpose: [n][d] -> [d][n]
// Vt with the PV k-permutation baked into each 64-key tile:
// tile position p*8+i  <-  k = 32*(p>>2) + 16*(i>>2) + 4*(p&3) + (i&3)
__global__ void k_vtrans(const unsigned short* __restrict__ proj,
                         unsigned short* __restrict__ Vt) {
    __shared__ unsigned short Ls[64][136];
    const int h = blockIdx.y;
    const int n0 = blockIdx.x * 64;
    const int t = threadIdx.x;
    #pragma unroll
    for (int i = 0; i < 4; ++i) {
        int ch = i * 256 + t;
        int r = ch >> 4, d0 = (ch & 15) * 8;
        uint4 v = *(const uint4*)&proj[(size_t)(n0 + r) * (3 * EDIM) + 2 * EDIM + h * HD + d0];
        *(uint4*)&Ls[r][d0] = v;
    }
    __syncthreads();
    #pragma unroll
    for (int i = 0; i < 4; ++i) {
        int ch = i * 256 + t;
        int d = ch >> 3, p = ch & 7;
        unsigned short vals[8];
        #pragma unroll
        for (int j = 0; j < 8; ++j) {
            int ko = 32 * (p >> 2) + 16 * (j >> 2) + 4 * (p & 3) + (j & 3);
            vals[j] = Ls[ko][d];
        }
        uint4 pk;
        pk.x = (unsigned)vals[0] | ((unsigned)vals[1] << 16);
        pk.y = (unsigned)vals[2] | ((unsigned)vals[3] << 16);
        pk.z = (unsigned)vals[4] | ((unsigned)vals[5] << 16);
        pk.w = (unsigned)vals[6] | ((unsigned)vals[7] << 16);
        *(uint4*)&Vt[((size_t)h * HD + d) * N_SEQ + n0 + p * 8] = pk;
    }
}

// ------------------------------------------------------- polynomial attention
// round-8 version (best measured: 115 us): swapped QK^T keeps P in registers,
// permuted-V single-b128 B-frags, unroll-2 dbuf, vmcnt(8), setprio.
__launch_bounds__(256, 2)
__global__ void k_attn(const unsigned short* __restrict__ Qh,
                       const unsigned short* __restrict__ Kh,
                       const unsigned short* __restrict__ Vt,
                       unsigned short* __restrict__ O) {
    __shared__ unsigned short pool[4 * 8192];

    const int t = threadIdx.x;
    const int w = t >> 6, lane = t & 63;
    const int lg = lane >> 4, lr = lane & 15;

    const int s = blockIdx.x & 255;
    const int batch = blockIdx.x >> 8;
    const int x = s & 7;
    const int hb = (s >> 3) & 1;
    const int h = x * 2 + hb;
    const int qq = s >> 4;
    const int qb = batch ? qq : (31 - qq);
    const int q0 = qb * 128;
    const int qbase = q0 + w * 32;

    bf16x8 qf[2][4];
    #pragma unroll
    for (int mi = 0; mi < 2; ++mi)
        #pragma unroll
        for (int kk = 0; kk < 4; ++kk)
            qf[mi][kk] = *(const bf16x8*)&Qh[((size_t)h * N_SEQ + qbase + mi * 16 + lr) * HD + kk * 32 + lg * 8];

    f32x4 acc[2][8];
    #pragma unroll
    for (int i = 0; i < 2; ++i)
        #pragma unroll
        for (int j = 0; j < 8; ++j) acc[i][j] = f32x4{0.f, 0.f, 0.f, 0.f};
    f32x4 accd[2];
    accd[0] = f32x4{0.f, 0.f, 0.f, 0.f};
    accd[1] = f32x4{0.f, 0.f, 0.f, 0.f};

    bf16x8 onesf;
    {
        short ov = (lr == 0) ? (short)0x3F80 : (short)0;
        #pragma unroll
        for (int j = 0; j < 8; ++j) onesf[j] = ov;
    }

    int kch[4], vch[4];
    const unsigned short* kg[4];
    const unsigned short* vg[4];
    #pragma unroll
    for (int i = 0; i < 4; ++i) {
        int ch = i * 256 + t;
        kch[i] = ch;
        int r = ch >> 4, p = ch & 15;
        int csrc = (p & 8) | ((p ^ r) & 7);
        kg[i] = Kh + ((size_t)h * N_SEQ + r) * HD + csrc * 8;
    }
    #pragma unroll
    for (int i = 0; i < 4; ++i) {
        int ch = i * 256 + t;
        vch[i] = ch;
        int d = ch >> 3, p2 = ch & 7;
        int c2src = (p2 ^ d) & 7;
        vg[i] = Vt + ((size_t)h * HD + d) * N_SEQ + c2src * 8;
    }

    const int nkb = 2 * qb + 2;   // always even

    union U8 { unsigned u[4]; bf16x8 v; };

    auto stage = [&](unsigned short* Kn, unsigned short* Vn) {
        #pragma unroll
        for (int i = 0; i < 4; ++i) { gll16(kg[i], Kn + kch[i] * 8); kg[i] += 64 * HD; }
        #pragma unroll
        for (int i = 0; i < 4; ++i) { gll16(vg[i], Vn + vch[i] * 8); vg[i] += 64; }
    };

    auto compute = [&](int k0, const unsigned short* Kc, const unsigned short* Vc) {
        f32x4 sa[2][4];
        #pragma unroll
        for (int i = 0; i < 2; ++i)
            #pragma unroll
            for (int j = 0; j < 4; ++j) sa[i][j] = f32x4{0.f, 0.f, 0.f, 0.f};
        #pragma unroll
        for (int nn = 0; nn < 2; ++nn) {
            bf16x8 kf[2][4];
            #pragma unroll
            for (int nj = 0; nj < 2; ++nj)
                #pragma unroll
                for (int kk = 0; kk < 4; ++kk) {
                    int row = (nn * 2 + nj) * 16 + lr;
                    int c = kk * 4 + lg;
                    int cs = (c & 8) | ((c ^ row) & 7);
                    kf[nj][kk] = *(const bf16x8*)&Kc[row * 128 + cs * 8];
                }
            __builtin_amdgcn_s_setprio(1);
            #pragma unroll
            for (int kk = 0; kk < 4; ++kk)
                #pragma unroll
                for (int nj = 0; nj < 2; ++nj)
                    #pragma unroll
                    for (int mi = 0; mi < 2; ++mi)
                        sa[mi][nn * 2 + nj] = __builtin_amdgcn_mfma_f32_16x16x32_bf16(
                            kf[nj][kk], qf[mi][kk], sa[mi][nn * 2 + nj], 0, 0, 0);
            __builtin_amdgcn_s_setprio(0);
        }

        unsigned wreg[2][4][2];
        const bool nomask = (k0 + 63 <= qbase);
        #pragma unroll
        for (int mi = 0; mi < 2; ++mi)
            #pragma unroll
            for (int nj = 0; nj < 4; ++nj) {
                float p[4];
                #pragma unroll
                for (int r = 0; r < 4; ++r) {
                    float sv = sa[mi][nj][r];
                    float t2 = sv * sv;
                    p[r] = t2 * t2;
                    if (!nomask) {
                        int gk = k0 + nj * 16 + lg * 4 + r;
                        int gq = qbase + mi * 16 + lr;
                        p[r] = (gk <= gq) ? p[r] : 0.0f;
                    }
                }
                asm("v_cvt_pk_bf16_f32 %0, %1, %2" : "=v"(wreg[mi][nj][0]) : "v"(p[0]), "v"(p[1]));
                asm("v_cvt_pk_bf16_f32 %0, %1, %2" : "=v"(wreg[mi][nj][1]) : "v"(p[2]), "v"(p[3]));
            }

        #pragma unroll
        for (int s2 = 0; s2 < 2; ++s2) {
            bf16x8 pa[2];
            #pragma unroll
            for (int mi = 0; mi < 2; ++mi) {
                U8 u;
                u.u[0] = wreg[mi][2 * s2][0];
                u.u[1] = wreg[mi][2 * s2][1];
                u.u[2] = wreg[mi][2 * s2 + 1][0];
                u.u[3] = wreg[mi][2 * s2 + 1][1];
                pa[mi] = u.v;
            }
            __builtin_amdgcn_s_setprio(1);
            #pragma unroll
            for (int ni = 0; ni < 8; ++ni) {
                int d = ni * 16 + lr;
                int cs = ((s2 * 4 + lg) ^ (d & 7)) & 7;
                bf16x8 vf = *(const bf16x8*)&Vc[d * 64 + cs * 8];
                #pragma unroll
                for (int mi = 0; mi < 2; ++mi)
                    acc[mi][ni] = __builtin_amdgcn_mfma_f32_16x16x32_bf16(pa[mi], vf, acc[mi][ni], 0, 0, 0);
            }
            #pragma unroll
            for (int mi = 0; mi < 2; ++mi)
                accd[mi] = __builtin_amdgcn_mfma_f32_16x16x32_bf16(pa[mi], onesf, accd[mi], 0, 0, 0);
            __builtin_amdgcn_s_setprio(0);
        }
    };

    stage(pool, pool + 16384);

    for (int kb = 0; kb < nkb; kb += 2) {
        stage(pool + 8192, pool + 16384 + 8192);
        asm volatile("s_waitcnt vmcnt(8)" ::: "memory");
        __builtin_amdgcn_s_barrier();
        compute(kb * 64, pool, pool + 16384);
        __builtin_amdgcn_s_barrier();
        if (kb + 2 < nkb) {
            stage(pool, pool + 16384);
            asm volatile("s_waitcnt vmcnt(8)" ::: "memory");
        } else {
            asm volatile("s_waitcnt vmcnt(0)" ::: "memory");
        }
        __builtin_amdgcn_s_barrier();
        compute((kb + 1) * 64, pool + 8192, pool + 16384 + 8192);
        __builtin_amdgcn_s_barrier();
    }

    unsigned short* Cs = pool;   // [128][128]
    #pragma unroll
    for (int mi = 0; mi < 2; ++mi) {
        #pragma unroll
        for (int r = 0; r < 4; ++r) {
            float dv = __shfl(accd[mi][r], lane & 48);
            float rinv = 1.0f / dv;
            int rw = w * 32 + mi * 16 + lg * 4 + r;
            #pragma unroll
            for (int ni = 0; ni < 8; ++ni)
                Cs[rw * 128 + ni * 16 + lr] = f2bf(acc[mi][ni][r] * rinv);
        }
    }
    __syncthreads();
    #pragma unroll
    for (int i = 0; i < 8; ++i) {
        int ch = i * 256 + t;
        int row = ch >> 4, c8 = (ch & 15) * 8;
        *(uint4*)&O[(size_t)(q0 + row) * EDIM + h * HD + c8] = *(const uint4*)&Cs[row * 128 + c8];
    }
}

// ---------------------------------------------------------------- launch
extern "C" void kernel_launch(void* const* d_in, const int* in_sizes, int n_in,
                              void* d_out, int out_size, void* d_ws, size_t ws_size,
                              hipStream_t stream) {
    const float* x        = (const float*)d_in[0];
    const float* w_qkv    = (const float*)d_in[1];
    const float* w_out    = (const float*)d_in[2];
    const float* ln_scale = (const float*)d_in[3];
    const float* ln_bias  = (const float*)d_in[4];

    if (ws_size < 134217728u) return;  // need 128 MiB

    char* ws = (char*)d_ws;
    unsigned short* xb    = (unsigned short*)(ws);              // 16 MiB; reused as attnO
    unsigned short* wqkvT = (unsigned short*)(ws + 16777216);   // 24 MiB; reused as Qh
    unsigned short* woutT = (unsigned short*)(ws + 41943040);   //  8 MiB
    unsigned short* proj  = (unsigned short*)(ws + 50331648);   // 48 MiB
    unsigned short* Kh    = (unsigned short*)(ws + 100663296);  // 16 MiB
    unsigned short* Vt    = (unsigned short*)(ws + 117440512);  // 16 MiB
    unsigned short* Qh    = wqkvT;   // alias: w_qkvT dead after GEMM1
    unsigned short* attnO = xb;      // alias: xb dead after GEMM1

    k_convert_x<<<2048, 256, 0, stream>>>(x, xb, (N_SEQ * EDIM) / 4);
    k_transpose_f32_bf16<<<dim3(3 * EDIM / 64, EDIM / 64), 256, 0, stream>>>(w_qkv, wqkvT, EDIM, 3 * EDIM);
    k_transpose_f32_bf16<<<dim3(EDIM / 64, EDIM / 64), 256, 0, stream>>>(w_out, woutT, EDIM, EDIM);
    k_gemm256_bt<<<dim3(3 * EDIM / 256, N_SEQ / 256), 512, 0, stream>>>(xb, wqkvT, proj, N_SEQ, 3 * EDIM, EDIM);
    k_ropeln<<<N_SEQ, 256, 0, stream>>>(proj, ln_scale, ln_bias, Qh, Kh);
    k_vtrans<<<dim3(N_SEQ / 64, NH), 256, 0, stream>>>(proj, Vt);
    k_attn<<<512, 256, 0, stream>>>(Qh, Kh, Vt, attnO);
    k_gemm_bt<1><<<dim3(EDIM / 128, N_SEQ / 128), 256, 0, stream>>>(attnO, woutT, (float*)d_out, N_SEQ, EDIM, EDIM);
}

// Round 12
// 286.331 us; speedup vs baseline: 1.1447x; 1.0590x over previous
//
#include <hip/hip_runtime.h>
#include <stdint.h>
#include <math.h>

// Problem constants
#define N_SEQ 4096
#define EDIM  2048
#define NH    16
#define HD    128

typedef __attribute__((ext_vector_type(8))) short bf16x8;
typedef __attribute__((ext_vector_type(4))) float f32x4;

#define AS1 __attribute__((address_space(1)))
#define AS3 __attribute__((address_space(3)))

__device__ __forceinline__ void gll16(const unsigned short* g, unsigned short* l) {
    __builtin_amdgcn_global_load_lds((const AS1 unsigned int*)g,
                                     (AS3 unsigned int*)l, 16, 0, 0);
}

__device__ __forceinline__ unsigned short f2bf(float f) {
    union { float f; unsigned u; } v; v.f = f;
    unsigned r = v.u + 0x7FFFu + ((v.u >> 16) & 1u);
    return (unsigned short)(r >> 16);
}
__device__ __forceinline__ float bf2f(unsigned short h) {
    union { unsigned u; float f; } v; v.u = ((unsigned)h) << 16;
    return v.f;
}

// ---------------------------------------------------------------- convert x
__global__ void k_convert_x(const float* __restrict__ x,
                            unsigned short* __restrict__ xb, int n4) {
    int i = blockIdx.x * blockDim.x + threadIdx.x;
    int stride = gridDim.x * blockDim.x;
    for (; i < n4; i += stride) {
        float4 v = ((const float4*)x)[i];
        ushort4 o;
        o.x = f2bf(v.x); o.y = f2bf(v.y); o.z = f2bf(v.z); o.w = f2bf(v.w);
        ((ushort4*)xb)[i] = o;
    }
}

// ---------------------------------------------- transpose f32 (RxC) -> bf16 (CxR)
__global__ void k_transpose_f32_bf16(const float* __restrict__ in,
                                     unsigned short* __restrict__ out,
                                     int R, int C) {
    __shared__ unsigned short Ls[64][68];
    const int c0 = blockIdx.x * 64, r0 = blockIdx.y * 64;
    const int t = threadIdx.x;
    #pragma unroll
    for (int i = 0; i < 4; ++i) {
        int ch = i * 256 + t;              // 1024 float4 chunks
        int r = ch >> 4, c4 = (ch & 15) * 4;
        float4 v = *(const float4*)&in[(size_t)(r0 + r) * C + c0 + c4];
        ushort4 o;
        o.x = f2bf(v.x); o.y = f2bf(v.y); o.z = f2bf(v.z); o.w = f2bf(v.w);
        *(ushort4*)&Ls[r][c4] = o;
    }
    __syncthreads();
    #pragma unroll
    for (int i = 0; i < 2; ++i) {
        int ch = i * 256 + t;              // 512 chunks of 8 bf16
        int rr = ch >> 3, c8 = (ch & 7) * 8;
        unsigned short vals[8];
        #pragma unroll
        for (int j = 0; j < 8; ++j) vals[j] = Ls[c8 + j][rr];
        uint4 pk;
        pk.x = (unsigned)vals[0] | ((unsigned)vals[1] << 16);
        pk.y = (unsigned)vals[2] | ((unsigned)vals[3] << 16);
        pk.z = (unsigned)vals[4] | ((unsigned)vals[5] << 16);
        pk.w = (unsigned)vals[6] | ((unsigned)vals[7] << 16);
        *(uint4*)&out[(size_t)(c0 + rr) * R + r0 + c8] = pk;
    }
}

// ---------------------------------------------------------------- bt GEMM (m97)
// C[M,N] = A[M,K] * Bt[N,K]^T  (bf16 in, f32 acc, bf16 or f32 out)
template<int F32OUT>
__launch_bounds__(256, 2)
__global__ void k_gemm_bt(const unsigned short* __restrict__ A,
                          const unsigned short* __restrict__ Bt,
                          void* __restrict__ C,
                          int M, int N, int K) {
    __shared__ unsigned short sh[2 * 128 * 64];   // As | Bs, linear [128][64]
    unsigned short* As = sh;
    unsigned short* Bs = sh + 128 * 64;

    const int t = threadIdx.x;
    const int wave = t >> 6, lane = t & 63;
    const int wm = wave >> 1, wn = wave & 1;
    const int lg = lane >> 4, lr = lane & 15;

    const int nbx = gridDim.x;
    const int nwg = nbx * gridDim.y;
    int bid = blockIdx.y * nbx + blockIdx.x;
    int swz = (bid & 7) * (nwg >> 3) + (bid >> 3);
    const int m0 = (swz / nbx) * 128;
    const int n0 = (swz % nbx) * 128;

    const unsigned short* aptr = A  + (size_t)m0 * K;
    const unsigned short* bptr = Bt + (size_t)n0 * K;

    f32x4 acc[4][4];
    #pragma unroll
    for (int i = 0; i < 4; ++i)
        #pragma unroll
        for (int j = 0; j < 4; ++j) acc[i][j] = f32x4{0.f, 0.f, 0.f, 0.f};

    int schr[4], srow[4], scb[4];
    #pragma unroll
    for (int i = 0; i < 4; ++i) {
        int ch = (i * 4 + wave) * 64 + lane;
        schr[i] = ch;
        srow[i] = ch >> 3;
        scb[i]  = (ch & 7) ^ ((ch >> 3) & 7);
    }

    const int nkb = K >> 6;
    for (int kb = 0; kb < nkb; ++kb) {
        __syncthreads();
        #pragma unroll
        for (int i = 0; i < 4; ++i) {
            const size_t goff = (size_t)srow[i] * K + (size_t)kb * 64 + scb[i] * 8;
            gll16(&aptr[goff], &As[schr[i] * 8]);
            gll16(&bptr[goff], &Bs[schr[i] * 8]);
        }
        __syncthreads();

        #pragma unroll
        for (int kk = 0; kk < 2; ++kk) {
            bf16x8 af[4], bf[4];
            const int cbx = ((kk * 4 + lg) ^ (lr & 7)) * 8;
            #pragma unroll
            for (int i = 0; i < 4; ++i) {
                af[i] = *(const bf16x8*)&As[(wm * 64 + i * 16 + lr) * 64 + cbx];
                bf[i] = *(const bf16x8*)&Bs[(wn * 64 + i * 16 + lr) * 64 + cbx];
            }
            #pragma unroll
            for (int i = 0; i < 4; ++i)
                #pragma unroll
                for (int j = 0; j < 4; ++j)
                    acc[i][j] = __builtin_amdgcn_mfma_f32_16x16x32_bf16(af[i], bf[j], acc[i][j], 0, 0, 0);
        }
    }

    if (F32OUT) {
        #pragma unroll
        for (int i = 0; i < 4; ++i) {
            int row0 = m0 + wm * 64 + i * 16 + lg * 4;
            #pragma unroll
            for (int j = 0; j < 4; ++j) {
                int col = n0 + wn * 64 + j * 16 + lr;
                #pragma unroll
                for (int r = 0; r < 4; ++r)
                    ((float*)C)[(size_t)(row0 + r) * N + col] = acc[i][j][r];
            }
        }
    } else {
        __syncthreads();
        unsigned short* Cs = sh;     // [128][128]
        #pragma unroll
        for (int i = 0; i < 4; ++i) {
            #pragma unroll
            for (int j = 0; j < 4; ++j) {
                int col = wn * 64 + j * 16 + lr;
                #pragma unroll
                for (int r = 0; r < 4; ++r)
                    Cs[(wm * 64 + i * 16 + lg * 4 + r) * 128 + col] = f2bf(acc[i][j][r]);
            }
        }
        __syncthreads();
        #pragma unroll
        for (int i = 0; i < 8; ++i) {
            int ch = i * 256 + t;
            int row = ch >> 4, c8 = (ch & 15) * 8;
            *(uint4*)&((unsigned short*)C)[(size_t)(m0 + row) * N + n0 + c8] =
                *(const uint4*)&Cs[row * 128 + c8];
        }
    }
}

// ------------------------------------------------------- RoPE + LayerNorm (q,k)
__global__ void k_ropeln(const unsigned short* __restrict__ proj,
                         const float* __restrict__ ln_scale,
                         const float* __restrict__ ln_bias,
                         unsigned short* __restrict__ Qh,
                         unsigned short* __restrict__ Kh) {
    const int n = blockIdx.x;
    const int wave = threadIdx.x >> 6, lane = threadIdx.x & 63;
    float inv = expf(-((float)(2 * lane) / 128.0f) * 9.210340371976184f);
    float ang = (float)n * inv;
    float c = cosf(ang), s = sinf(ang);
    const float sc1 = ln_scale[lane], sc2 = ln_scale[lane + 64];
    const float b1 = ln_bias[lane],  b2 = ln_bias[lane + 64];

    for (int r = wave; r < 32; r += 4) {
        int h = r >> 1, qk = r & 1;
        const unsigned short* src = proj + (size_t)n * (3 * EDIM) + qk * EDIM + h * HD;
        float x1 = bf2f(src[lane]), x2 = bf2f(src[lane + 64]);
        float o1 = x1 * c - x2 * s;
        float o2 = x1 * s + x2 * c;
        float sum = o1 + o2, sq = o1 * o1 + o2 * o2;
        #pragma unroll
        for (int d = 1; d < 64; d <<= 1) {
            sum += __shfl_xor(sum, d);
            sq  += __shfl_xor(sq, d);
        }
        float mean = sum * (1.0f / 128.0f);
        float var = sq * (1.0f / 128.0f) - mean * mean;
        float rstd = rsqrtf(var + 1e-5f);
        float y1 = (o1 - mean) * rstd * sc1 + b1;
        float y2 = (o2 - mean) * rstd * sc2 + b2;
        unsigned short* dst = (qk ? Kh : Qh) + ((size_t)h * N_SEQ + n) * HD;
        dst[lane]      = f2bf(y1);
        dst[lane + 64] = f2bf(y2);
    }
}

// ---------------------------------------------------- V transpose: [n][d] -> [d][n]
// Vt with the PV k-permutation baked into each 64-key tile:
// tile position p*8+i  <-  k = 32*(p>>2) + 16*(i>>2) + 4*(p&3) + (i&3)
__global__ void k_vtrans(const unsigned short* __restrict__ proj,
                         unsigned short* __restrict__ Vt) {
    __shared__ unsigned short Ls[64][136];
    const int h = blockIdx.y;
    const int n0 = blockIdx.x * 64;
    const int t = threadIdx.x;
    #pragma unroll
    for (int i = 0; i < 4; ++i) {
        int ch = i * 256 + t;
        int r = ch >> 4, d0 = (ch & 15) * 8;
        uint4 v = *(const uint4*)&proj[(size_t)(n0 + r) * (3 * EDIM) + 2 * EDIM + h * HD + d0];
        *(uint4*)&Ls[r][d0] = v;
    }
    __syncthreads();
    #pragma unroll
    for (int i = 0; i < 4; ++i) {
        int ch = i * 256 + t;
        int d = ch >> 3, p = ch & 7;
        unsigned short vals[8];
        #pragma unroll
        for (int j = 0; j < 8; ++j) {
            int ko = 32 * (p >> 2) + 16 * (j >> 2) + 4 * (p & 3) + (j & 3);
            vals[j] = Ls[ko][d];
        }
        uint4 pk;
        pk.x = (unsigned)vals[0] | ((unsigned)vals[1] << 16);
        pk.y = (unsigned)vals[2] | ((unsigned)vals[3] << 16);
        pk.z = (unsigned)vals[4] | ((unsigned)vals[5] << 16);
        pk.w = (unsigned)vals[6] | ((unsigned)vals[7] << 16);
        *(uint4*)&Vt[((size_t)h * HD + d) * N_SEQ + n0 + p * 8] = pk;
    }
}

// ------------------------------------------------------- polynomial attention
// v10: k-split across waves. Block = 64 q-rows, 4 waves = (wq q-half) x
// (wk k-half). Each wave computes 32q x 32k per tile -> reads HALF of K and
// HALF of V (16 ds_read_b128/iter vs 32): LDS traffic per unit work halved
// (the measured bottleneck). f32 accumulator combine between wk-pairs via
// LDS once at the end (pure reassociation). In-register P (swapped QK^T +
// cvt_pk into PV A-frags, permuted-Vt single-b128 B-frags) as round 8.
// 1024 blocks, LPT heavy-first, 2 blocks/CU.
__launch_bounds__(256, 2)
__global__ void k_attn(const unsigned short* __restrict__ Qh,
                       const unsigned short* __restrict__ Kh,
                       const unsigned short* __restrict__ Vt,
                       unsigned short* __restrict__ O) {
    // K[2][64][128] | V[2][128][64] = 64 KB; epilogue reuses as Xf(36KB)+Cs(16KB)
    __shared__ unsigned short pool[4 * 8192];

    const int t = threadIdx.x;
    const int w = t >> 6, lane = t & 63;
    const int wq = w >> 1, wk = w & 1;
    const int lg = lane >> 4, lr = lane & 15;

    // LPT dispatch: heavy q-tiles first. b&7 = XCD = h>>1 (2 heads/XCD).
    const int b = blockIdx.x;
    const int h = (b & 7) * 2 + ((b >> 3) & 1);
    const int qt = 63 - (b >> 4);
    const int q0 = qt * 64;
    const int qbase = q0 + wq * 32;   // this wave's first q-row
    const int kbase = wk * 32;        // this wave's k-offset within a tile

    // Q fragments (wave's 32 queries x 128 d)
    bf16x8 qf[2][4];
    #pragma unroll
    for (int mi = 0; mi < 2; ++mi)
        #pragma unroll
        for (int kk = 0; kk < 4; ++kk)
            qf[mi][kk] = *(const bf16x8*)&Qh[((size_t)h * N_SEQ + qbase + mi * 16 + lr) * HD + kk * 32 + lg * 8];

    f32x4 acc[2][8];
    #pragma unroll
    for (int i = 0; i < 2; ++i)
        #pragma unroll
        for (int j = 0; j < 8; ++j) acc[i][j] = f32x4{0.f, 0.f, 0.f, 0.f};
    f32x4 accd[2];
    accd[0] = f32x4{0.f, 0.f, 0.f, 0.f};
    accd[1] = f32x4{0.f, 0.f, 0.f, 0.f};

    // ones B-fragment: row-sum lands in output col 0 (k-permutation-invariant)
    bf16x8 onesf;
    {
        short ov = (lr == 0) ? (short)0x3F80 : (short)0;
        #pragma unroll
        for (int j = 0; j < 8; ++j) onesf[j] = ov;
    }

    // staging: per tile K 64x128 (1024 chunks, 4/thr) + V 128x64 (1024, 4/thr)
    int kch[4], vch[4];
    const unsigned short* kg[4];
    const unsigned short* vg[4];
    #pragma unroll
    for (int i = 0; i < 4; ++i) {
        int ch = i * 256 + t;
        kch[i] = ch;
        int r = ch >> 4, p = ch & 15;
        int csrc = (p & 8) | ((p ^ r) & 7);
        kg[i] = Kh + ((size_t)h * N_SEQ + r) * HD + csrc * 8;
    }
    #pragma unroll
    for (int i = 0; i < 4; ++i) {
        int ch = i * 256 + t;
        vch[i] = ch;
        int d = ch >> 3, p2 = ch & 7;
        int c2src = (p2 ^ d) & 7;
        vg[i] = Vt + ((size_t)h * HD + d) * N_SEQ + c2src * 8;
    }

    const int nkb = qt + 1;

    union U8 { unsigned u[4]; bf16x8 v; };

    auto stage = [&](unsigned short* Kn, unsigned short* Vn) {
        #pragma unroll
        for (int i = 0; i < 4; ++i) { gll16(kg[i], Kn + kch[i] * 8); kg[i] += 64 * HD; }
        #pragma unroll
        for (int i = 0; i < 4; ++i) { gll16(vg[i], Vn + vch[i] * 8); vg[i] += 64; }
    };

    auto compute = [&](int k0, const unsigned short* Kc, const unsigned short* Vc) {
        if (k0 + kbase > qbase + 31) return;   // wave's k-half fully masked
        // ---- S^T = K Q^T (swapped): lane holds S[k0+kbase+16nj+4lg+r][qbase+16mi+lr]
        f32x4 sa[2][2];
        #pragma unroll
        for (int i = 0; i < 2; ++i) {
            sa[i][0] = f32x4{0.f, 0.f, 0.f, 0.f};
            sa[i][1] = f32x4{0.f, 0.f, 0.f, 0.f};
        }
        bf16x8 kf[2][4];
        #pragma unroll
        for (int nj = 0; nj < 2; ++nj)
            #pragma unroll
            for (int kk = 0; kk < 4; ++kk) {
                int row = kbase + nj * 16 + lr;
                int c = kk * 4 + lg;
                int cs = (c & 8) | ((c ^ row) & 7);
                kf[nj][kk] = *(const bf16x8*)&Kc[row * 128 + cs * 8];
            }
        __builtin_amdgcn_s_setprio(1);
        #pragma unroll
        for (int kk = 0; kk < 4; ++kk)
            #pragma unroll
            for (int nj = 0; nj < 2; ++nj)
                #pragma unroll
                for (int mi = 0; mi < 2; ++mi)
                    sa[mi][nj] = __builtin_amdgcn_mfma_f32_16x16x32_bf16(
                        kf[nj][kk], qf[mi][kk], sa[mi][nj], 0, 0, 0);
        __builtin_amdgcn_s_setprio(0);

        // ---- mask + ^4 + pack to bf16 pairs in registers
        unsigned wreg[2][2][2];
        const bool nomask = (k0 + kbase + 31 <= qbase);
        #pragma unroll
        for (int mi = 0; mi < 2; ++mi)
            #pragma unroll
            for (int nj = 0; nj < 2; ++nj) {
                float p[4];
                #pragma unroll
                for (int r = 0; r < 4; ++r) {
                    float sv = sa[mi][nj][r];
                    float t2 = sv * sv;
                    p[r] = t2 * t2;
                    if (!nomask) {
                        int gk = k0 + kbase + nj * 16 + lg * 4 + r;
                        int gq = qbase + mi * 16 + lr;
                        p[r] = (gk <= gq) ? p[r] : 0.0f;
                    }
                }
                asm("v_cvt_pk_bf16_f32 %0, %1, %2" : "=v"(wreg[mi][nj][0]) : "v"(p[0]), "v"(p[1]));
                asm("v_cvt_pk_bf16_f32 %0, %1, %2" : "=v"(wreg[mi][nj][1]) : "v"(p[2]), "v"(p[3]));
            }

        // ---- O += P V (k-half), denom += P * ones
        bf16x8 pa[2];
        #pragma unroll
        for (int mi = 0; mi < 2; ++mi) {
            U8 u;
            u.u[0] = wreg[mi][0][0];
            u.u[1] = wreg[mi][0][1];
            u.u[2] = wreg[mi][1][0];
            u.u[3] = wreg[mi][1][1];
            pa[mi] = u.v;
        }
        __builtin_amdgcn_s_setprio(1);
        #pragma unroll
        for (int ni = 0; ni < 8; ++ni) {
            int d = ni * 16 + lr;
            int cs = ((wk * 4 + lg) ^ (d & 7)) & 7;
            bf16x8 vf = *(const bf16x8*)&Vc[d * 64 + cs * 8];
            #pragma unroll
            for (int mi = 0; mi < 2; ++mi)
                acc[mi][ni] = __builtin_amdgcn_mfma_f32_16x16x32_bf16(pa[mi], vf, acc[mi][ni], 0, 0, 0);
        }
        #pragma unroll
        for (int mi = 0; mi < 2; ++mi)
            accd[mi] = __builtin_amdgcn_mfma_f32_16x16x32_bf16(pa[mi], onesf, accd[mi], 0, 0, 0);
        __builtin_amdgcn_s_setprio(0);
    };

    // prologue: stage tile 0 into buf 0
    stage(pool, pool + 16384);
    int kb0 = 0;
    if (nkb & 1) {
        asm volatile("s_waitcnt vmcnt(0)" ::: "memory");
        __builtin_amdgcn_s_barrier();
        compute(0, pool, pool + 16384);
        __builtin_amdgcn_s_barrier();
        if (nkb > 1) stage(pool, pool + 16384);   // tile 1 -> buf0
        kb0 = 1;
    }
    for (int kb = kb0; kb < nkb; kb += 2) {
        stage(pool + 8192, pool + 16384 + 8192);  // tile kb+1 -> buf1
        asm volatile("s_waitcnt vmcnt(8)" ::: "memory");
        __builtin_amdgcn_s_barrier();
        compute(kb * 64, pool, pool + 16384);
        __builtin_amdgcn_s_barrier();
        if (kb + 2 < nkb) {
            stage(pool, pool + 16384);            // tile kb+2 -> buf0
            asm volatile("s_waitcnt vmcnt(8)" ::: "memory");
        } else {
            asm volatile("s_waitcnt vmcnt(0)" ::: "memory");
        }
        __builtin_amdgcn_s_barrier();
        compute((kb + 1) * 64, pool + 8192, pool + 16384 + 8192);
        __builtin_amdgcn_s_barrier();
    }

    // ---- combine wk halves (f32 add via LDS, slot-major conflict-free) ----
    asm volatile("s_waitcnt vmcnt(0)" ::: "memory");   // drain stray prefetches
    __syncthreads();
    float* Xf = (float*)pool;                 // [wq][18 slots][64 lanes][4] f32
    const int xbase = wq * 4608 + lane * 4;
    if (wk == 1) {
        #pragma unroll
        for (int mi = 0; mi < 2; ++mi) {
            #pragma unroll
            for (int ni = 0; ni < 8; ++ni)
                *(f32x4*)&Xf[xbase + (mi * 8 + ni) * 256] = acc[mi][ni];
            *(f32x4*)&Xf[xbase + (16 + mi) * 256] = accd[mi];
        }
    }
    __syncthreads();
    unsigned short* Cs = pool + 20480;        // [64][128] bf16, disjoint from Xf
    if (wk == 0) {
        #pragma unroll
        for (int mi = 0; mi < 2; ++mi) {
            #pragma unroll
            for (int ni = 0; ni < 8; ++ni) {
                f32x4 o = *(const f32x4*)&Xf[xbase + (mi * 8 + ni) * 256];
                acc[mi][ni][0] += o[0]; acc[mi][ni][1] += o[1];
                acc[mi][ni][2] += o[2]; acc[mi][ni][3] += o[3];
            }
            f32x4 od = *(const f32x4*)&Xf[xbase + (16 + mi) * 256];
            accd[mi][0] += od[0]; accd[mi][1] += od[1];
            accd[mi][2] += od[2]; accd[mi][3] += od[3];
        }
        // divide + stage bf16 tile
        #pragma unroll
        for (int mi = 0; mi < 2; ++mi) {
            #pragma unroll
            for (int r = 0; r < 4; ++r) {
                float dv = __shfl(accd[mi][r], lane & 48);  // col 0 in lane lg*16
                float rinv = 1.0f / dv;
                int rw = wq * 32 + mi * 16 + lg * 4 + r;
                #pragma unroll
                for (int ni = 0; ni < 8; ++ni)
                    Cs[rw * 128 + ni * 16 + lr] = f2bf(acc[mi][ni][r] * rinv);
            }
        }
    }
    __syncthreads();
    #pragma unroll
    for (int i = 0; i < 4; ++i) {
        int ch = i * 256 + t;                 // 1024 chunks of 8 shorts
        int row = ch >> 4, c8 = (ch & 15) * 8;
        *(uint4*)&O[(size_t)(q0 + row) * EDIM + h * HD + c8] = *(const uint4*)&Cs[row * 128 + c8];
    }
}

// ---------------------------------------------------------------- launch
extern "C" void kernel_launch(void* const* d_in, const int* in_sizes, int n_in,
                              void* d_out, int out_size, void* d_ws, size_t ws_size,
                              hipStream_t stream) {
    const float* x        = (const float*)d_in[0];
    const float* w_qkv    = (const float*)d_in[1];
    const float* w_out    = (const float*)d_in[2];
    const float* ln_scale = (const float*)d_in[3];
    const float* ln_bias  = (const float*)d_in[4];

    if (ws_size < 134217728u) return;  // need 128 MiB

    char* ws = (char*)d_ws;
    unsigned short* xb    = (unsigned short*)(ws);              // 16 MiB; reused as attnO
    unsigned short* wqkvT = (unsigned short*)(ws + 16777216);   // 24 MiB; reused as Qh
    unsigned short* woutT = (unsigned short*)(ws + 41943040);   //  8 MiB
    unsigned short* proj  = (unsigned short*)(ws + 50331648);   // 48 MiB
    unsigned short* Kh    = (unsigned short*)(ws + 100663296);  // 16 MiB
    unsigned short* Vt    = (unsigned short*)(ws + 117440512);  // 16 MiB
    unsigned short* Qh    = wqkvT;   // alias: w_qkvT dead after GEMM1
    unsigned short* attnO = xb;      // alias: xb dead after GEMM1

    k_convert_x<<<2048, 256, 0, stream>>>(x, xb, (N_SEQ * EDIM) / 4);
    k_transpose_f32_bf16<<<dim3(3 * EDIM / 64, EDIM / 64), 256, 0, stream>>>(w_qkv, wqkvT, EDIM, 3 * EDIM);
    k_transpose_f32_bf16<<<dim3(EDIM / 64, EDIM / 64), 256, 0, stream>>>(w_out, woutT, EDIM, EDIM);
    k_gemm_bt<0><<<dim3(3 * EDIM / 128, N_SEQ / 128), 256, 0, stream>>>(xb, wqkvT, proj, N_SEQ, 3 * EDIM, EDIM);
    k_ropeln<<<N_SEQ, 256, 0, stream>>>(proj, ln_scale, ln_bias, Qh, Kh);
    k_vtrans<<<dim3(N_SEQ / 64, NH), 256, 0, stream>>>(proj, Vt);
    k_attn<<<1024, 256, 0, stream>>>(Qh, Kh, Vt, attnO);
    k_gemm_bt<1><<<dim3(EDIM / 128, N_SEQ / 128), 256, 0, stream>>>(attnO, woutT, (float*)d_out, N_SEQ, EDIM, EDIM);
}